// Round 8
// baseline (2005.270 us; speedup 1.0000x reference)
//
#include <hip/hip_runtime.h>

#define B_ 4
#define N_ 8192
#define DIN 64
#define HDIM 64
#define DOUT 128
#define KNN 16
#define QPB 64
#define NTHR 512
#define BLOCKS_PER_B (N_ / QPB)  // 128
#define MG 1e-3f   // certified slack: >> max abs rounding error of the d chain

// ---------------- K_prep: pack (x,y,z,sq) + compose affine params ----------------
__global__ __launch_bounds__(256) void k_prep(
    const float* __restrict__ xyz,
    const float* __restrict__ w1, const float* __restrict__ b1,
    const float* __restrict__ w2, const float* __restrict__ b2,
    const float* __restrict__ w3, const float* __restrict__ b3,
    float4* __restrict__ pk, float4* __restrict__ prm) {
  const int blk = blockIdx.x, t = threadIdx.x;
  const int b = blk >> 5;
  const int m = ((blk & 31) << 8) + t;
  const float* xb = xyz + (size_t)b * 3 * N_;
  float x = xb[m], y = xb[N_ + m], z = xb[2 * N_ + m];
  float sq = __fadd_rn(__fadd_rn(__fmul_rn(x, x), __fmul_rn(y, y)), __fmul_rn(z, z));
  pk[((size_t)b << 13) + m] = make_float4(x, y, z, sq);

  if (blk == 0) {
    __shared__ float M2[HDIM][10];
    __shared__ float bb[HDIM];
    const int o = t;
    if (o < HDIM) {
      float r[10];
#pragma unroll
      for (int c = 0; c < 10; c++) r[c] = 0.f;
      float s = b2[o];
      for (int l = 0; l < HDIM; l++) {
        float w = w2[o * HDIM + l];
#pragma unroll
        for (int c = 0; c < 10; c++) r[c] = fmaf(w, w1[l * 10 + c], r[c]);
        s = fmaf(w, b1[l], s);
      }
#pragma unroll
      for (int c = 0; c < 10; c++) M2[o][c] = r[c];
      bb[o] = s;
    }
    __syncthreads();
    if (o < HDIM) {
      float r3[10];
#pragma unroll
      for (int c = 0; c < 10; c++) r3[c] = 0.f;
      float bc = b3[o];
      for (int l = 0; l < HDIM; l++) {
        float w = w3[o * HDIM + l];
#pragma unroll
        for (int c = 0; c < 10; c++) r3[c] = fmaf(w, M2[l][c], r3[c]);
        bc = fmaf(w, bb[l], bc);
      }
      prm[o]      = make_float4(r3[0] - r3[6], r3[1] - r3[7], r3[2] - r3[8], bc);
      prm[64 + o] = make_float4(r3[3] + r3[6], r3[4] + r3[7], r3[5] + r3[8], r3[9]);
    }
  }
}

// ---------------- K_sort: per batch, bitonic sort by x; pks into out rows 8..11 --
__global__ __launch_bounds__(512) void k_sort(const float4* __restrict__ pk,
                                              float* __restrict__ out) {
  const int b = blockIdx.x;
  const int t = threadIdx.x;
  const size_t bq = (size_t)b << 13;
  __shared__ float kx[N_];            // 32 KB
  __shared__ unsigned short ki[N_];   // 16 KB
  for (int i = t; i < N_; i += 512) { kx[i] = pk[bq + i].x; ki[i] = (unsigned short)i; }
  __syncthreads();
  for (unsigned k = 2; k <= (unsigned)N_; k <<= 1) {
    for (unsigned jj = k >> 1; jj > 0; jj >>= 1) {
      for (unsigned i = t; i < (unsigned)N_; i += 512) {
        unsigned l = i ^ jj;
        if (l > i) {
          float a = kx[i], c = kx[l];
          bool up = ((i & k) == 0u);
          if ((a > c) == up) {
            unsigned short ia = ki[i];
            kx[i] = c; kx[l] = a;
            ki[i] = ki[l]; ki[l] = ia;
          }
        }
      }
      __syncthreads();
    }
  }
  // emit sorted (x,y,z,bitcast(origIdx)); sq is recomputed bit-exactly later
  float4* pks = (float4*)(out + (size_t)b * DOUT * N_ + 8 * N_);  // rows 8..11
  for (int p = t; p < N_; p += 512) {
    int oi = ki[p];
    float4 c = pk[bq + oi];
    pks[p] = make_float4(c.x, c.y, c.z, __uint_as_float((unsigned)oi));
  }
}

// max of 16 via v_max3-friendly triple nesting
#define MAX16(VARR, VMAX)                                                     \
  {                                                                           \
    float _m0 = fmaxf(fmaxf(VARR[0], VARR[1]), VARR[2]);                      \
    float _m1 = fmaxf(fmaxf(VARR[3], VARR[4]), VARR[5]);                      \
    float _m2 = fmaxf(fmaxf(VARR[6], VARR[7]), VARR[8]);                      \
    float _m3 = fmaxf(fmaxf(VARR[9], VARR[10]), VARR[11]);                    \
    float _m4 = fmaxf(fmaxf(VARR[12], VARR[13]), VARR[14]);                   \
    float _a = fmaxf(fmaxf(_m0, _m1), _m2);                                   \
    float _b = fmaxf(fmaxf(_m3, _m4), VARR[15]);                              \
    VMAX = fmaxf(_a, _b);                                                     \
  }

// per-lane predicated replace-max insert (ACC = this lane accepts)
#define INSERT16A(ACC, VARR, IARR, VMAX, DVAL, MIDX)              \
  {                                                               \
    bool done = !(ACC);                                           \
    _Pragma("unroll") for (int _i = 0; _i < KNN; _i++) {          \
      bool hit = (!done) && (VARR[_i] == VMAX);                   \
      if (hit) { VARR[_i] = (DVAL); IARR[_i] = (MIDX); }          \
      done = done | hit;                                          \
    }                                                             \
    MAX16(VARR, VMAX);                                            \
  }

// exact reference-rounded distance: sq chain identical to k_prep, then
// d = fmaf(-2,dot,qs+cs) == (qs+cs) - 2*dot bit-exactly (2*dot exact in fp32)
#define DCHAIN(C, D, MO)                                                      \
  float cs = __fadd_rn(__fadd_rn(__fmul_rn((C).x, (C).x),                     \
                                 __fmul_rn((C).y, (C).y)),                    \
                       __fmul_rn((C).z, (C).z));                              \
  float dot = fmaf((C).z, qz, fmaf((C).y, qy, __fmul_rn((C).x, qx)));         \
  float D = fmaf(-2.0f, dot, __fadd_rn(qs, cs));                              \
  int MO = (int)__float_as_uint((C).w);

// ---------------- K_knn: per-lane exact kNN over the x-sorted array -----------
// lane = one sorted query; seed window [s-16,s+16] (>=17 valid everywhere, so
// all 16 slots fill), then expand each side until fl(dx^2) > vmax + MG -- a
// certified bound (d_ref >= dx^2_true - 5e-5 and dx monotone in sorted order),
// so no true top-16 member is ever pruned. Adjacent lanes have adjacent s ->
// overlapping windows -> gathers are L1-resident; depth-2 clamped prefetch.
__global__ __launch_bounds__(256) void k_knn(float* __restrict__ out) {
  const int blk = blockIdx.x;
  const int b = blk >> 5;                       // 32 blocks per batch
  const int s = ((blk & 31) << 8) + threadIdx.x;
  float* obase = out + (size_t)b * DOUT * N_;
  const float4* pks = (const float4*)(obase + 8 * N_);

  const float4 qc = pks[s];
  const float qx = qc.x, qy = qc.y, qz = qc.z;
  const float qs = __fadd_rn(__fadd_rn(__fmul_rn(qx, qx), __fmul_rn(qy, qy)),
                             __fmul_rn(qz, qz));
  const unsigned mq = __float_as_uint(qc.w);

  const float INF = __uint_as_float(0x7f800000u);
  float v[KNN]; int id[KNN];
#pragma unroll
  for (int i = 0; i < KNN; i++) { v[i] = INF; id[i] = 0; }
  float vmax = INF;

  // seeds: sorted window [s-16, s+16] (self included; clamped loads, masked hits)
  for (int off = -16; off <= 16; ++off) {
    int p = s + off;
    bool val = ((unsigned)p < (unsigned)N_);
    float4 c = pks[val ? p : 0];
    DCHAIN(c, d, mo)
    bool hit = val && (d < vmax);
    if (__any(hit)) { INSERT16A(hit, v, id, vmax, d, mo); }
  }

  // expand left (x decreasing; dx = qx - cx >= 0, monotone nondecreasing)
  {
    int L = s - 17;
    bool alv = (L >= 0);
    float4 c0 = pks[max(L, 0)];
    float4 c1 = pks[max(L - 1, 0)];
    while (__any(alv)) {
      float4 c2 = pks[max(L - 2, 0)];
      float dx = __fsub_rn(qx, c0.x);
      float dxx = __fmul_rn(dx, dx);
      if (dxx > vmax + MG) alv = false;   // certified stop for this side
      DCHAIN(c0, d, mo)
      bool hit = alv && (d < vmax);
      if (__any(hit)) { INSERT16A(hit, v, id, vmax, d, mo); }
      L -= 1;
      alv = alv && (L >= 0);
      c0 = c1; c1 = c2;
    }
  }
  // expand right (x increasing; dx = cx - qx >= 0)
  {
    int R = s + 17;
    bool alv = (R <= N_ - 1);
    float4 c0 = pks[min(R, N_ - 1)];
    float4 c1 = pks[min(R + 1, N_ - 1)];
    while (__any(alv)) {
      float4 c2 = pks[min(R + 2, N_ - 1)];
      float dx = __fsub_rn(c0.x, qx);
      float dxx = __fmul_rn(dx, dx);
      if (dxx > vmax + MG) alv = false;
      DCHAIN(c0, d, mo)
      bool hit = alv && (d < vmax);
      if (__any(hit)) { INSERT16A(hit, v, id, vmax, d, mo); }
      R += 1;
      alv = alv && (R <= N_ - 1);
      c0 = c1; c1 = c2;
    }
  }

  // write 16 orig-index ids packed 2-per-float into rows 0..7, column mq
  float* ob = obase + mq;
#pragma unroll
  for (int r = 0; r < 8; r++) {
    unsigned pv = ((unsigned)id[2 * r] & 0xFFFFu) |
                  (((unsigned)id[2 * r + 1] & 0xFFFFu) << 16);
    ob[(size_t)r * N_] = __uint_as_float(pv);
  }
}

// ---------------- K_fe: gather + fe + shortcut GEMM ---------------------------
__global__ __launch_bounds__(NTHR, 2) void k_fe(
    const float4* __restrict__ pk, const float4* __restrict__ prm,
    const float* __restrict__ feature, const float* __restrict__ wsM,
    const float* __restrict__ bs, float* __restrict__ out) {
  const int blk = blockIdx.x;
  const int b  = blk / BLOCKS_PER_B;
  const int n0 = (blk % BLOCKS_PER_B) * QPB;
  const int t = threadIdx.x;
  const int q = t & 63;
  const int j = __builtin_amdgcn_readfirstlane(t >> 6);
  const size_t bb = (size_t)b << 13;
  const float INF = __uint_as_float(0x7f800000u);

  __shared__ float4 prmL[2 * HDIM];              // 2 KB
  __shared__ float gp[4 * KNN * QPB];            // 16 KB: neighbor x/y/z/dsq rows
  __shared__ float feL[DIN * QPB];               // 16 KB feature tile
  __shared__ alignas(16) float wsL[DOUT * DIN];  // 32 KB ws

  for (int i = t; i < 2 * HDIM; i += NTHR) prmL[i] = prm[i];
  for (int i = t; i < DOUT * DIN / 4; i += NTHR)
    ((float4*)wsL)[i] = ((const float4*)wsM)[i];
#pragma unroll
  for (int r = 0; r < 8; r++) {
    int c = j * 8 + r;
    feL[c * QPB + q] = feature[(size_t)(b * DIN + c) * N_ + n0 + q];
  }

  const float4 qv = pk[bb + n0 + q];
  const float qx = qv.x, qy = qv.y, qz = qv.z;

  float* ob = out + (size_t)b * DOUT * N_ + n0 + q;

  // read this wave's id pair (row j), gather 2 neighbors into gp rows
  unsigned prb = __float_as_uint(ob[(size_t)j * N_]);
#pragma unroll
  for (int kk = 0; kk < 2; kk++) {
    int k = j * 2 + kk;
    int m = (int)((kk ? (prb >> 16) : prb) & 0xFFFFu) & (N_ - 1);
    float4 c = pk[bb + m];
    float dx = __fsub_rn(c.x, qx), dy = __fsub_rn(c.y, qy), dz = __fsub_rn(c.z, qz);
    float dsq = __fadd_rn(__fadd_rn(__fmul_rn(dx, dx), __fmul_rn(dy, dy)),
                          __fmul_rn(dz, dz));
    gp[k * QPB + q] = c.x;
    gp[(KNN + k) * QPB + q] = c.y;
    gp[(2 * KNN + k) * QPB + q] = c.z;
    gp[(3 * KNN + k) * QPB + q] = dsq;
  }
  __syncthreads();

  float fo[8];
  {
    float nx[KNN], ny[KNN], nz[KNN], nd[KNN];
#pragma unroll
    for (int k = 0; k < KNN; k++) {
      nx[k] = gp[k * QPB + q];
      ny[k] = gp[(KNN + k) * QPB + q];
      nz[k] = gp[(2 * KNN + k) * QPB + q];
      nd[k] = gp[(3 * KNN + k) * QPB + q];
    }
#pragma unroll
    for (int oi = 0; oi < 8; oi++) {
      int o = j * 8 + oi;
      float4 pA = prmL[o], pB = prmL[HDIM + o];
      float basev = fmaf(qz, pA.z, fmaf(qy, pA.y, fmaf(qx, pA.x, pA.w)));
      float mx = -INF;
#pragma unroll
      for (int k = 0; k < KNN; k++) {
        float tv = fmaf(nz[k], pB.z,
                   fmaf(ny[k], pB.y,
                   fmaf(nx[k], pB.x, __fmul_rn(nd[k], pB.w))));
        mx = fmaxf(mx, tv);
      }
      fo[oi] = basev + mx;
    }
  }

  // shortcut GEMM: wave j computes outputs o=j*8..j*8+7 and o+64 for its query q
  float acc[16];
#pragma unroll
  for (int oi = 0; oi < 16; oi++) acc[oi] = 0.f;
  for (int c4 = 0; c4 < DIN / 4; c4++) {
    float f0 = feL[(4 * c4 + 0) * QPB + q];
    float f1 = feL[(4 * c4 + 1) * QPB + q];
    float f2 = feL[(4 * c4 + 2) * QPB + q];
    float f3 = feL[(4 * c4 + 3) * QPB + q];
#pragma unroll
    for (int oi = 0; oi < 16; oi++) {
      int o = (oi < 8) ? (j * 8 + oi) : (64 + j * 8 + oi - 8);
      float4 w = ((const float4*)(wsL + o * DIN))[c4];  // wave-uniform broadcast
      acc[oi] = fmaf(w.x, f0, acc[oi]);
      acc[oi] = fmaf(w.y, f1, acc[oi]);
      acc[oi] = fmaf(w.z, f2, acc[oi]);
      acc[oi] = fmaf(w.w, f3, acc[oi]);
    }
  }
#pragma unroll
  for (int oi = 0; oi < 16; oi++) {
    int o = (oi < 8) ? (j * 8 + oi) : (64 + j * 8 + oi - 8);
    ob[(size_t)o * N_] = acc[oi] + bs[o] + fo[oi & 7];
  }
}

extern "C" void kernel_launch(void* const* d_in, const int* in_sizes, int n_in,
                              void* d_out, int out_size, void* d_ws, size_t ws_size,
                              hipStream_t stream) {
  const float* xyz     = (const float*)d_in[0];
  const float* feature = (const float*)d_in[1];
  const float* w1 = (const float*)d_in[2];
  const float* b1 = (const float*)d_in[3];
  const float* w2 = (const float*)d_in[4];
  const float* b2 = (const float*)d_in[5];
  const float* w3 = (const float*)d_in[6];
  const float* b3 = (const float*)d_in[7];
  const float* wsM = (const float*)d_in[8];
  const float* bs  = (const float*)d_in[9];
  float* out = (float*)d_out;

  // workspace: [0,8KB) prm, [8KB, 8KB+512KB) packed pk (orig order).
  // sorted pks lives in out rows 8..11 per batch (scratch, overwritten by k_fe).
  float4* prm = (float4*)d_ws;
  float4* pkB = (float4*)((char*)d_ws + 8192);

  hipLaunchKernelGGL(k_prep, dim3(128), dim3(256), 0, stream,
                     xyz, w1, b1, w2, b2, w3, b3, pkB, prm);
  hipLaunchKernelGGL(k_sort, dim3(B_), dim3(512), 0, stream, pkB, out);
  hipLaunchKernelGGL(k_knn, dim3(B_ * 32), dim3(256), 0, stream, out);
  hipLaunchKernelGGL(k_fe, dim3(B_ * BLOCKS_PER_B), dim3(NTHR), 0, stream,
                     pkB, prm, feature, wsM, bs, out);
}

// Round 9
// 548.396 us; speedup vs baseline: 3.6566x; 3.6566x over previous
//
#include <hip/hip_runtime.h>

#define B_ 4
#define N_ 8192
#define DIN 64
#define HDIM 64
#define DOUT 128
#define KNN 16
#define QPB 64
#define NTHR 512
#define BLOCKS_PER_B (N_ / QPB)  // 128
#define MG 1e-3f                 // certified slack >> d-chain rounding (~5e-5)
#define BW 0.0390625f            // bucket width: 10/256
#define NBKT 256

// out-row scratch layout per batch (obase = out + b*DOUT*N_):
//  rows 8..11 : pks float4[8192]  (bucket-x-sorted points, w = exact sq)
//  row 12     : sidx ushort[8192] (sorted pos -> original index)
//  row 13     : hist int[256] | cnt2 int[256] | offs int[257]

// ---------------- K_prep: pack (x,y,z,sq) + x-histogram + affine params -------
__global__ __launch_bounds__(256) void k_prep(
    const float* __restrict__ xyz,
    const float* __restrict__ w1, const float* __restrict__ b1,
    const float* __restrict__ w2, const float* __restrict__ b2,
    const float* __restrict__ w3, const float* __restrict__ b3,
    float4* __restrict__ pk, float4* __restrict__ prm, float* __restrict__ out) {
  const int blk = blockIdx.x, t = threadIdx.x;
  const int b = blk >> 5;
  const int m = ((blk & 31) << 8) + t;
  const float* xb = xyz + (size_t)b * 3 * N_;
  float x = xb[m], y = xb[N_ + m], z = xb[2 * N_ + m];
  float sq = __fadd_rn(__fadd_rn(__fmul_rn(x, x), __fmul_rn(y, y)), __fmul_rn(z, z));
  pk[((size_t)b << 13) + m] = make_float4(x, y, z, sq);

  // fused x-histogram (LDS aggregate -> global atomics; counters pre-zeroed)
  __shared__ int histL[NBKT];
  histL[t] = 0;
  __syncthreads();
  int bi = (int)((x + 5.0f) * 25.6f);
  bi = bi < 0 ? 0 : (bi > 255 ? 255 : bi);
  atomicAdd(&histL[bi], 1);
  __syncthreads();
  {
    int* hist = (int*)(out + (size_t)b * DOUT * N_ + 13 * (size_t)N_);
    if (histL[t] > 0) atomicAdd(&hist[t], histL[t]);
  }

  if (blk == 0) {
    __shared__ float M2[HDIM][10];
    __shared__ float bb[HDIM];
    const int o = t;
    if (o < HDIM) {
      float r[10];
#pragma unroll
      for (int c = 0; c < 10; c++) r[c] = 0.f;
      float s = b2[o];
      for (int l = 0; l < HDIM; l++) {
        float w = w2[o * HDIM + l];
#pragma unroll
        for (int c = 0; c < 10; c++) r[c] = fmaf(w, w1[l * 10 + c], r[c]);
        s = fmaf(w, b1[l], s);
      }
#pragma unroll
      for (int c = 0; c < 10; c++) M2[o][c] = r[c];
      bb[o] = s;
    }
    __syncthreads();
    if (o < HDIM) {
      float r3[10];
#pragma unroll
      for (int c = 0; c < 10; c++) r3[c] = 0.f;
      float bc = b3[o];
      for (int l = 0; l < HDIM; l++) {
        float w = w3[o * HDIM + l];
#pragma unroll
        for (int c = 0; c < 10; c++) r3[c] = fmaf(w, M2[l][c], r3[c]);
        bc = fmaf(w, bb[l], bc);
      }
      prm[o]      = make_float4(r3[0] - r3[6], r3[1] - r3[7], r3[2] - r3[8], bc);
      prm[64 + o] = make_float4(r3[3] + r3[6], r3[4] + r3[7], r3[5] + r3[8], r3[9]);
    }
  }
}

// ---------------- K_scatter: counting-sort by x-bucket into out scratch -------
__global__ __launch_bounds__(256) void k_scatter(const float4* __restrict__ pk,
                                                 float* __restrict__ out) {
  const int blk = blockIdx.x, t = threadIdx.x;
  const int b = blk >> 5;
  const int m = ((blk & 31) << 8) + t;
  float* obase = out + (size_t)b * DOUT * N_;
  float4* pks = (float4*)(obase + 8 * (size_t)N_);
  unsigned short* sidx = (unsigned short*)(obase + 12 * (size_t)N_);
  int* hist = (int*)(obase + 13 * (size_t)N_);
  int* cnt2 = hist + NBKT;
  int* offs = hist + 2 * NBKT;

  __shared__ int histL[NBKT];
  __shared__ int offsL[NBKT + 1];
  histL[t] = hist[t];
  __syncthreads();
  if (t == 0) {
    int acc = 0;
    for (int i = 0; i < NBKT; i++) { offsL[i] = acc; acc += histL[i]; }
    offsL[NBKT] = acc;
  }
  __syncthreads();
  if ((blk & 31) == 0) {
    for (int i = t; i < NBKT + 1; i += 256) offs[i] = offsL[i];  // same values/block
  }
  float4 c = pk[((size_t)b << 13) + m];
  int bi = (int)((c.x + 5.0f) * 25.6f);
  bi = bi < 0 ? 0 : (bi > 255 ? 255 : bi);
  int pos = offsL[bi] + atomicAdd(&cnt2[bi], 1);
  pks[pos] = c;
  sidx[pos] = (unsigned short)m;
}

// max of 16 via v_max3-friendly triple nesting
#define MAX16(VARR, VMAX)                                                     \
  {                                                                           \
    float _m0 = fmaxf(fmaxf(VARR[0], VARR[1]), VARR[2]);                      \
    float _m1 = fmaxf(fmaxf(VARR[3], VARR[4]), VARR[5]);                      \
    float _m2 = fmaxf(fmaxf(VARR[6], VARR[7]), VARR[8]);                      \
    float _m3 = fmaxf(fmaxf(VARR[9], VARR[10]), VARR[11]);                    \
    float _m4 = fmaxf(fmaxf(VARR[12], VARR[13]), VARR[14]);                   \
    float _a = fmaxf(fmaxf(_m0, _m1), _m2);                                   \
    float _b = fmaxf(fmaxf(_m3, _m4), VARR[15]);                              \
    VMAX = fmaxf(_a, _b);                                                     \
  }

// per-lane predicated replace-max insert (ACC = this lane accepts)
#define INSERT16A(ACC, VARR, IARR, VMAX, DVAL, MIDX)              \
  {                                                               \
    bool done = !(ACC);                                           \
    _Pragma("unroll") for (int _i = 0; _i < KNN; _i++) {          \
      bool hit = (!done) && (VARR[_i] == VMAX);                   \
      if (hit) { VARR[_i] = (DVAL); IARR[_i] = (MIDX); }          \
      done = done | hit;                                          \
    }                                                             \
    MAX16(VARR, VMAX);                                            \
  }

// exact reference-rounded d: sq is precomputed (c.w, bit-exact k_prep chain);
// d = fmaf(-2,dot,qs+cs) == (qs+cs) - 2*dot bit-exactly (2*dot exact in fp32)
#define DCALC(C, D)                                                           \
  float dot = fmaf((C).z, qz, fmaf((C).y, qy, __fmul_rn((C).x, qx)));         \
  float D = fmaf(-2.0f, dot, __fadd_rn(qs, (C).w));

// ---------------- K_knn: windowed partner-wave broadcast scan -----------------
// block g: 64 bucket-sorted queries s=s0+q across 8 waves. Wave 0 broadcast-
// seeds positions [SA,SB] (96 x-near candidates) -> per-query vmax_seed (a
// certified upper bound on the true 16NN d). Certified window from bucket
// offsets: any true neighbor has |dx| <= sqrt(vmax_seed) -> bucket range
// [bL,bR] -> positions [iL,iRx). Waves 0-3 sweep the left remainder outward,
// 4-7 the right, 8 broadcast candidates/batch (wave-uniform s_loads, R4-proven
// engine), direct per-lane INSERT16A (hits are rare under the tight seed gate),
// with certified per-wave early-exit: (|dx|-BW)^2 > vmax+MG for all lanes
// (BW slack covers within-bucket x-disorder).
__global__ __launch_bounds__(NTHR) void k_knn(float* __restrict__ out) {
  const int blk = blockIdx.x;
  const int b = blk >> 7;
  const int g = blk & 127;
  const int s0 = g * QPB;
  const int t = threadIdx.x;
  const int q = t & 63;
  const int j = __builtin_amdgcn_readfirstlane(t >> 6);
  float* obase = out + (size_t)b * DOUT * N_;
  const float4* pks = (const float4*)(obase + 8 * (size_t)N_);
  const unsigned short* sidx = (const unsigned short*)(obase + 12 * (size_t)N_);
  const int* offs = (const int*)(obase + 13 * (size_t)N_) + 2 * NBKT;

  __shared__ float tau[QPB];
  __shared__ float Xd[4 * KNN * QPB];            // 16 KB merge exchange
  __shared__ unsigned short Xi[4 * KNN * QPB];   // 8 KB

  const int s = s0 + q;
  const float4 qv = pks[s];
  const float qx = qv.x, qy = qv.y, qz = qv.z, qs = qv.w;

  const float INF = __uint_as_float(0x7f800000u);
  float v[KNN]; int id[KNN];
#pragma unroll
  for (int i = 0; i < KNN; i++) { v[i] = INF; id[i] = 0; }
  float vmax = INF;

  const int SA = max(0, s0 - 16), SB = min(N_ - 1, s0 + 79);

  // ---- seed (wave 0): broadcast scan of [SA,SB]; count is a multiple of 8 ----
  if (j == 0) {
    for (int p0 = SA; p0 <= SB; p0 += 8) {
      float4 c[8];
#pragma unroll
      for (int e = 0; e < 8; e++) c[e] = pks[p0 + e];
#pragma unroll
      for (int e = 0; e < 8; e++) {
        DCALC(c[e], d)
        bool hit = (d < vmax);
        if (__any(hit)) { INSERT16A(hit, v, id, vmax, d, p0 + e); }
      }
    }
    tau[q] = vmax;
  }
  __syncthreads();
  const float gate0 = tau[q];

  // ---- certified window via bucket offsets ----
  float W = sqrtf(gate0 + MG);
  float xl = qx - W, xr = qx + W;
#pragma unroll
  for (int o = 1; o < 64; o <<= 1) {
    xl = fminf(xl, __shfl_xor(xl, o));
    xr = fmaxf(xr, __shfl_xor(xr, o));
  }
  int bL = (int)((xl + 5.0f) * 25.6f); bL = bL < 0 ? 0 : (bL > 255 ? 255 : bL);
  int bR = (int)((xr + 5.0f) * 25.6f); bR = bR < 0 ? 0 : (bR > 255 ? 255 : bR);
  int iL = __builtin_amdgcn_readfirstlane(offs[bL]);
  int iRx = __builtin_amdgcn_readfirstlane(offs[bR + 1]);
  const int L1 = max(0, SA - iL);          // left remainder  [iL, SA-1], outward
  const int L2 = max(0, iRx - (SB + 1));   // right remainder [SB+1, iRx), outward

  // ---- expansion: waves 0-3 left, 4-7 right; strided outward batches ----
  {
    const bool left = (j < 4);
    const int jj = left ? j : (j - 4);
    const int Ln = left ? L1 : L2;
    for (int ci0 = jj * 8; ci0 < Ln; ci0 += 32) {
      float4 c[8]; int pa[8];
#pragma unroll
      for (int e = 0; e < 8; e++) {
        int cic = min(ci0 + e, Ln - 1);
        int p = left ? (SA - 1 - cic) : (SB + 1 + cic);
        pa[e] = p; c[e] = pks[p];
      }
#pragma unroll
      for (int e = 0; e < 8; e++) {
        DCALC(c[e], d)
        bool hit = (ci0 + e < Ln) && (d < fminf(vmax, gate0));
        if (__any(hit)) { INSERT16A(hit, v, id, vmax, d, pa[e]); }
      }
      // certified early-exit: farthest candidate of this batch, minus bucket
      // disorder slack, already beyond every lane's running bound
      float adx = fabsf(__fsub_rn(qx, c[7].x));
      float ar = fmaxf(adx - BW, 0.0f);
      if (__all(__fmul_rn(ar, ar) > vmax + MG)) break;
    }
  }
  __syncthreads();

  // ---- merge tree (R7-verified structure); INF slots fold away naturally ----
  // stage A: odd waves publish; even wave j folds wave j+1
  if (j & 1) {
    const int s_ = j >> 1;
#pragma unroll
    for (int i = 0; i < KNN; i++) {
      Xd[(s_ * KNN + i) * QPB + q] = v[i];
      Xi[(s_ * KNN + i) * QPB + q] = (unsigned short)id[i];
    }
  }
  __syncthreads();
  if (!(j & 1)) {
    const int s_ = j >> 1;
    for (int ss = 0; ss < KNN; ss++) {
      float d = Xd[(s_ * KNN + ss) * QPB + q];
      bool hit = (d < vmax);
      if (__any(hit)) {
        int m_ = Xi[(s_ * KNN + ss) * QPB + q];
        INSERT16A(hit, v, id, vmax, d, m_);
      }
    }
  }
  __syncthreads();
  // stage B: waves 2,6 publish slots 0,1; waves 0,4 fold
  if (j == 2 || j == 6) {
    const int s_ = j >> 2;
#pragma unroll
    for (int i = 0; i < KNN; i++) {
      Xd[(s_ * KNN + i) * QPB + q] = v[i];
      Xi[(s_ * KNN + i) * QPB + q] = (unsigned short)id[i];
    }
  }
  __syncthreads();
  if (j == 0 || j == 4) {
    const int s_ = j >> 2;
    for (int ss = 0; ss < KNN; ss++) {
      float d = Xd[(s_ * KNN + ss) * QPB + q];
      bool hit = (d < vmax);
      if (__any(hit)) {
        int m_ = Xi[(s_ * KNN + ss) * QPB + q];
        INSERT16A(hit, v, id, vmax, d, m_);
      }
    }
  }
  __syncthreads();
  // stage C: wave 4 publishes; wave 0 folds -> final, translate + store
  if (j == 4) {
#pragma unroll
    for (int i = 0; i < KNN; i++) {
      Xd[i * QPB + q] = v[i];
      Xi[i * QPB + q] = (unsigned short)id[i];
    }
  }
  __syncthreads();
  if (j == 0) {
    for (int ss = 0; ss < KNN; ss++) {
      float d = Xd[ss * QPB + q];
      bool hit = (d < vmax);
      if (__any(hit)) {
        int m_ = Xi[ss * QPB + q];
        INSERT16A(hit, v, id, vmax, d, m_);
      }
    }
    // translate sorted positions -> original ids; pack 2 per float, rows 0..7
    const unsigned mq = sidx[s];
    float* ob = obase + mq;
#pragma unroll
    for (int r = 0; r < 8; r++) {
      unsigned i0 = (unsigned)sidx[id[2 * r] & (N_ - 1)];
      unsigned i1 = (unsigned)sidx[id[2 * r + 1] & (N_ - 1)];
      ob[(size_t)r * N_] = __uint_as_float(i0 | (i1 << 16));
    }
  }
}

// ---------------- K_fe: gather + fe + shortcut GEMM (R8-verified) -------------
__global__ __launch_bounds__(NTHR, 2) void k_fe(
    const float4* __restrict__ pk, const float4* __restrict__ prm,
    const float* __restrict__ feature, const float* __restrict__ wsM,
    const float* __restrict__ bs, float* __restrict__ out) {
  const int blk = blockIdx.x;
  const int b  = blk / BLOCKS_PER_B;
  const int n0 = (blk % BLOCKS_PER_B) * QPB;
  const int t = threadIdx.x;
  const int q = t & 63;
  const int j = __builtin_amdgcn_readfirstlane(t >> 6);
  const size_t bb = (size_t)b << 13;
  const float INF = __uint_as_float(0x7f800000u);

  __shared__ float4 prmL[2 * HDIM];              // 2 KB
  __shared__ float gp[4 * KNN * QPB];            // 16 KB: neighbor x/y/z/dsq rows
  __shared__ float feL[DIN * QPB];               // 16 KB feature tile
  __shared__ alignas(16) float wsL[DOUT * DIN];  // 32 KB ws

  for (int i = t; i < 2 * HDIM; i += NTHR) prmL[i] = prm[i];
  for (int i = t; i < DOUT * DIN / 4; i += NTHR)
    ((float4*)wsL)[i] = ((const float4*)wsM)[i];
#pragma unroll
  for (int r = 0; r < 8; r++) {
    int c = j * 8 + r;
    feL[c * QPB + q] = feature[(size_t)(b * DIN + c) * N_ + n0 + q];
  }

  const float4 qv = pk[bb + n0 + q];
  const float qx = qv.x, qy = qv.y, qz = qv.z;

  float* ob = out + (size_t)b * DOUT * N_ + n0 + q;

  // read this wave's id pair (row j), gather 2 neighbors into gp rows
  unsigned prb = __float_as_uint(ob[(size_t)j * N_]);
#pragma unroll
  for (int kk = 0; kk < 2; kk++) {
    int k = j * 2 + kk;
    int m = (int)((kk ? (prb >> 16) : prb) & 0xFFFFu) & (N_ - 1);
    float4 c = pk[bb + m];
    float dx = __fsub_rn(c.x, qx), dy = __fsub_rn(c.y, qy), dz = __fsub_rn(c.z, qz);
    float dsq = __fadd_rn(__fadd_rn(__fmul_rn(dx, dx), __fmul_rn(dy, dy)),
                          __fmul_rn(dz, dz));
    gp[k * QPB + q] = c.x;
    gp[(KNN + k) * QPB + q] = c.y;
    gp[(2 * KNN + k) * QPB + q] = c.z;
    gp[(3 * KNN + k) * QPB + q] = dsq;
  }
  __syncthreads();

  float fo[8];
  {
    float nx[KNN], ny[KNN], nz[KNN], nd[KNN];
#pragma unroll
    for (int k = 0; k < KNN; k++) {
      nx[k] = gp[k * QPB + q];
      ny[k] = gp[(KNN + k) * QPB + q];
      nz[k] = gp[(2 * KNN + k) * QPB + q];
      nd[k] = gp[(3 * KNN + k) * QPB + q];
    }
#pragma unroll
    for (int oi = 0; oi < 8; oi++) {
      int o = j * 8 + oi;
      float4 pA = prmL[o], pB = prmL[HDIM + o];
      float basev = fmaf(qz, pA.z, fmaf(qy, pA.y, fmaf(qx, pA.x, pA.w)));
      float mx = -INF;
#pragma unroll
      for (int k = 0; k < KNN; k++) {
        float tv = fmaf(nz[k], pB.z,
                   fmaf(ny[k], pB.y,
                   fmaf(nx[k], pB.x, __fmul_rn(nd[k], pB.w))));
        mx = fmaxf(mx, tv);
      }
      fo[oi] = basev + mx;
    }
  }

  // shortcut GEMM: wave j computes outputs o=j*8..j*8+7 and o+64 for its query q
  float acc[16];
#pragma unroll
  for (int oi = 0; oi < 16; oi++) acc[oi] = 0.f;
  for (int c4 = 0; c4 < DIN / 4; c4++) {
    float f0 = feL[(4 * c4 + 0) * QPB + q];
    float f1 = feL[(4 * c4 + 1) * QPB + q];
    float f2 = feL[(4 * c4 + 2) * QPB + q];
    float f3 = feL[(4 * c4 + 3) * QPB + q];
#pragma unroll
    for (int oi = 0; oi < 16; oi++) {
      int o = (oi < 8) ? (j * 8 + oi) : (64 + j * 8 + oi - 8);
      float4 w = ((const float4*)(wsL + o * DIN))[c4];  // wave-uniform broadcast
      acc[oi] = fmaf(w.x, f0, acc[oi]);
      acc[oi] = fmaf(w.y, f1, acc[oi]);
      acc[oi] = fmaf(w.z, f2, acc[oi]);
      acc[oi] = fmaf(w.w, f3, acc[oi]);
    }
  }
#pragma unroll
  for (int oi = 0; oi < 16; oi++) {
    int o = (oi < 8) ? (j * 8 + oi) : (64 + j * 8 + oi - 8);
    ob[(size_t)o * N_] = acc[oi] + bs[o] + fo[oi & 7];
  }
}

extern "C" void kernel_launch(void* const* d_in, const int* in_sizes, int n_in,
                              void* d_out, int out_size, void* d_ws, size_t ws_size,
                              hipStream_t stream) {
  const float* xyz     = (const float*)d_in[0];
  const float* feature = (const float*)d_in[1];
  const float* w1 = (const float*)d_in[2];
  const float* b1 = (const float*)d_in[3];
  const float* w2 = (const float*)d_in[4];
  const float* b2 = (const float*)d_in[5];
  const float* w3 = (const float*)d_in[6];
  const float* b3 = (const float*)d_in[7];
  const float* wsM = (const float*)d_in[8];
  const float* bs  = (const float*)d_in[9];
  float* out = (float*)d_out;

  // workspace: [0,8KB) prm, [8KB, 8KB+512KB) packed pk (proven footprint).
  // Sorted pks/sidx/counters live in out rows 8..13 per batch (k_fe overwrites).
  float4* prm = (float4*)d_ws;
  float4* pkB = (float4*)((char*)d_ws + 8192);

  // zero hist+cnt2 (row 13, first 512 ints) per batch
  for (int b = 0; b < B_; b++)
    hipMemsetAsync(out + (size_t)b * DOUT * N_ + 13 * (size_t)N_, 0, 512 * 4, stream);

  hipLaunchKernelGGL(k_prep, dim3(128), dim3(256), 0, stream,
                     xyz, w1, b1, w2, b2, w3, b3, pkB, prm, out);
  hipLaunchKernelGGL(k_scatter, dim3(128), dim3(256), 0, stream, pkB, out);
  hipLaunchKernelGGL(k_knn, dim3(B_ * BLOCKS_PER_B), dim3(NTHR), 0, stream, out);
  hipLaunchKernelGGL(k_fe, dim3(B_ * BLOCKS_PER_B), dim3(NTHR), 0, stream,
                     pkB, prm, feature, wsM, bs, out);
}

// Round 10
// 377.905 us; speedup vs baseline: 5.3063x; 1.4511x over previous
//
#include <hip/hip_runtime.h>

#define B_ 4
#define N_ 8192
#define DIN 64
#define HDIM 64
#define DOUT 128
#define KNN 16
#define QPB 64
#define NTHR 512
#define BLOCKS_PER_B (N_ / QPB)  // 128
#define MG 1e-3f                 // certified slack >> d-chain rounding (~5e-5)
#define NBKT 256
#define CAP 16                   // deferred-push slots per thread
#define CAPP 17                  // padded per-lane stride
#define SEED 768                 // total seed positions (8 waves x 96)

// out-row scratch layout per batch (obase = out + b*DOUT*N_):
//  rows 8..11 : pks float4[8192]  (bucket-x-sorted points, w = exact sq)
//  row 12     : sidx ushort[8192] (sorted pos -> original index)
//  row 13     : hist int[256] | cnt2 int[256] | offs int[257]

// ---------------- K_prep: pack (x,y,z,sq) + x-histogram + affine params -------
__global__ __launch_bounds__(256) void k_prep(
    const float* __restrict__ xyz,
    const float* __restrict__ w1, const float* __restrict__ b1,
    const float* __restrict__ w2, const float* __restrict__ b2,
    const float* __restrict__ w3, const float* __restrict__ b3,
    float4* __restrict__ pk, float4* __restrict__ prm, float* __restrict__ out) {
  const int blk = blockIdx.x, t = threadIdx.x;
  const int b = blk >> 5;
  const int m = ((blk & 31) << 8) + t;
  const float* xb = xyz + (size_t)b * 3 * N_;
  float x = xb[m], y = xb[N_ + m], z = xb[2 * N_ + m];
  float sq = __fadd_rn(__fadd_rn(__fmul_rn(x, x), __fmul_rn(y, y)), __fmul_rn(z, z));
  pk[((size_t)b << 13) + m] = make_float4(x, y, z, sq);

  __shared__ int histL[NBKT];
  histL[t] = 0;
  __syncthreads();
  int bi = (int)((x + 5.0f) * 25.6f);
  bi = bi < 0 ? 0 : (bi > 255 ? 255 : bi);
  atomicAdd(&histL[bi], 1);
  __syncthreads();
  {
    int* hist = (int*)(out + (size_t)b * DOUT * N_ + 13 * (size_t)N_);
    if (histL[t] > 0) atomicAdd(&hist[t], histL[t]);
  }

  if (blk == 0) {
    __shared__ float M2[HDIM][10];
    __shared__ float bb[HDIM];
    const int o = t;
    if (o < HDIM) {
      float r[10];
#pragma unroll
      for (int c = 0; c < 10; c++) r[c] = 0.f;
      float s = b2[o];
      for (int l = 0; l < HDIM; l++) {
        float w = w2[o * HDIM + l];
#pragma unroll
        for (int c = 0; c < 10; c++) r[c] = fmaf(w, w1[l * 10 + c], r[c]);
        s = fmaf(w, b1[l], s);
      }
#pragma unroll
      for (int c = 0; c < 10; c++) M2[o][c] = r[c];
      bb[o] = s;
    }
    __syncthreads();
    if (o < HDIM) {
      float r3[10];
#pragma unroll
      for (int c = 0; c < 10; c++) r3[c] = 0.f;
      float bc = b3[o];
      for (int l = 0; l < HDIM; l++) {
        float w = w3[o * HDIM + l];
#pragma unroll
        for (int c = 0; c < 10; c++) r3[c] = fmaf(w, M2[l][c], r3[c]);
        bc = fmaf(w, bb[l], bc);
      }
      prm[o]      = make_float4(r3[0] - r3[6], r3[1] - r3[7], r3[2] - r3[8], bc);
      prm[64 + o] = make_float4(r3[3] + r3[6], r3[4] + r3[7], r3[5] + r3[8], r3[9]);
    }
  }
}

// ---------------- K_scatter: counting-sort by x-bucket into out scratch -------
__global__ __launch_bounds__(256) void k_scatter(const float4* __restrict__ pk,
                                                 float* __restrict__ out) {
  const int blk = blockIdx.x, t = threadIdx.x;
  const int b = blk >> 5;
  const int m = ((blk & 31) << 8) + t;
  float* obase = out + (size_t)b * DOUT * N_;
  float4* pks = (float4*)(obase + 8 * (size_t)N_);
  unsigned short* sidx = (unsigned short*)(obase + 12 * (size_t)N_);
  int* hist = (int*)(obase + 13 * (size_t)N_);
  int* cnt2 = hist + NBKT;
  int* offs = hist + 2 * NBKT;

  __shared__ int histL[NBKT];
  __shared__ int offsL[NBKT + 1];
  histL[t] = hist[t];
  __syncthreads();
  if (t == 0) {
    int acc = 0;
    for (int i = 0; i < NBKT; i++) { offsL[i] = acc; acc += histL[i]; }
    offsL[NBKT] = acc;
  }
  __syncthreads();
  if ((blk & 31) == 0) {
    for (int i = t; i < NBKT + 1; i += 256) offs[i] = offsL[i];
  }
  float4 c = pk[((size_t)b << 13) + m];
  int bi = (int)((c.x + 5.0f) * 25.6f);
  bi = bi < 0 ? 0 : (bi > 255 ? 255 : bi);
  int pos = offsL[bi] + atomicAdd(&cnt2[bi], 1);
  pks[pos] = c;
  sidx[pos] = (unsigned short)m;
}

// max of 16 via v_max3-friendly triple nesting
#define MAX16(VARR, VMAX)                                                     \
  {                                                                           \
    float _m0 = fmaxf(fmaxf(VARR[0], VARR[1]), VARR[2]);                      \
    float _m1 = fmaxf(fmaxf(VARR[3], VARR[4]), VARR[5]);                      \
    float _m2 = fmaxf(fmaxf(VARR[6], VARR[7]), VARR[8]);                      \
    float _m3 = fmaxf(fmaxf(VARR[9], VARR[10]), VARR[11]);                    \
    float _m4 = fmaxf(fmaxf(VARR[12], VARR[13]), VARR[14]);                   \
    float _a = fmaxf(fmaxf(_m0, _m1), _m2);                                   \
    float _b = fmaxf(fmaxf(_m3, _m4), VARR[15]);                              \
    VMAX = fmaxf(_a, _b);                                                     \
  }

// replace-max insert (always-insert form, for FLUSH drains)
#define INSERT16(VARR, IARR, VMAX, DVAL, MIDX)                    \
  {                                                               \
    bool done = false;                                            \
    _Pragma("unroll") for (int _i = 0; _i < KNN; _i++) {          \
      bool hit = (!done) && (VARR[_i] == VMAX);                   \
      if (hit) { VARR[_i] = (DVAL); IARR[_i] = (MIDX); }          \
      done = done | hit;                                          \
    }                                                             \
    MAX16(VARR, VMAX);                                            \
  }

// per-lane predicated replace-max insert (ACC = this lane accepts)
#define INSERT16A(ACC, VARR, IARR, VMAX, DVAL, MIDX)              \
  {                                                               \
    bool done = !(ACC);                                           \
    _Pragma("unroll") for (int _i = 0; _i < KNN; _i++) {          \
      bool hit = (!done) && (VARR[_i] == VMAX);                   \
      if (hit) { VARR[_i] = (DVAL); IARR[_i] = (MIDX); }          \
      done = done | hit;                                          \
    }                                                             \
    MAX16(VARR, VMAX);                                            \
  }

// exact reference-rounded d: sq precomputed (c.w, bit-exact k_prep chain);
// d = fmaf(-2,dot,qs+cs) == (qs+cs) - 2*dot bit-exactly (2*dot exact in fp32)
#define DCALC(C, D)                                                           \
  float dot = fmaf((C).z, qz, fmaf((C).y, qy, __fmul_rn((C).x, qx)));         \
  float D = fmaf(-2.0f, dot, __fadd_rn(qs, (C).w));

// drain deferred (d,idx) buffer -- LDS only; publish tau via returned old value
#define FLUSH()                                                   \
  {                                                               \
    for (int c_ = 0; c_ < cnt; c_++) {                            \
      float fd_ = poolF[lbase + c_];                              \
      int fm_ = poolI[lbase + c_];                                \
      if (fd_ < vmax) { INSERT16(v, id, vmax, fd_, fm_); }        \
    }                                                             \
    cnt = 0;                                                      \
    unsigned old_ = atomicMin(&tau[q], __float_as_uint(vmax));    \
    gate = fminf(vmax, __uint_as_float(old_));                    \
  }

// ---------------- K_knn: parallel seeds + certified window, R4 engine ---------
// block g: 64 bucket-sorted queries s=s0+q, 8 waves. (1) Wave j direct-inserts
// seed segment [base+j*96, +96) (disjoint, 768 total around s0) -> vmax_j;
// tau[q]=min_j vmax_j (each wave's 16th-smallest is an upper bound on d16).
// (2) Certified window via bucket offsets (|dx|<=sqrt(tau+MG)); the remainder
// [iL,base) u [base+768,iRx) is split contiguously across waves and scanned
// with the R4-proven deferred-push loop (exact-d filter, (d,idx) LDS push,
// FLUSH with evolving vmax + cross-wave tau). (3) R7-proven merge tree; sidx
// translation; packed id rows 0..7. __launch_bounds__(NTHR,4): the measured
// VGPR=64/no-spill configuration (R9's 32-VGPR spill was the 430us).
__global__ __launch_bounds__(NTHR, 4) void k_knn(float* __restrict__ out) {
  const int blk = blockIdx.x;
  const int b = blk >> 7;
  const int g = blk & 127;
  const int s0 = g * QPB;
  const int t = threadIdx.x;
  const int q = t & 63;
  const int j = __builtin_amdgcn_readfirstlane(t >> 6);
  const int lbase = t * CAPP;
  float* obase = out + (size_t)b * DOUT * N_;
  const float4* pks = (const float4*)(obase + 8 * (size_t)N_);
  const unsigned short* sidx = (const unsigned short*)(obase + 12 * (size_t)N_);
  const int* offs = (const int*)(obase + 13 * (size_t)N_) + 2 * NBKT;

  __shared__ unsigned tau[QPB];
  // 52.5 KB pool: scan (d,idx) buffers [512][17]; then merge Xd/Xi overlay
  __shared__ alignas(16) float poolF[CAPP * NTHR];
  __shared__ alignas(16) unsigned short poolI[CAPP * NTHR];
  float* Xd = poolF;                 // merge overlay: [128][64] floats (32KB)
  unsigned short* Xi = poolI;        // merge overlay: [128][64] ushort (16KB)

  if (t < QPB) tau[t] = 0x7f800000u;

  const int s = s0 + q;
  const float4 qv = pks[s];
  const float qx = qv.x, qy = qv.y, qz = qv.z, qs = qv.w;

  const float INF = __uint_as_float(0x7f800000u);
  float v[KNN]; int id[KNN];
#pragma unroll
  for (int i = 0; i < KNN; i++) { v[i] = INF; id[i] = 0; }
  float vmax = INF, gate;
  int cnt = 0;
  __syncthreads();

  // ---- phase 1: disjoint parallel seeds (wave j: 96 positions, 12 batches) ----
  const int base = min(max(s0 - 352, 0), N_ - SEED);
  {
    const int segb = base + j * 96;
    for (int p0 = segb; p0 < segb + 96; p0 += 8) {
      float4 c[8];
#pragma unroll
      for (int e = 0; e < 8; e++) c[e] = pks[p0 + e];  // wave-uniform s_loads
#pragma unroll
      for (int e = 0; e < 8; e++) {
        DCALC(c[e], d)
        bool hit = (d < vmax);
        if (__any(hit)) { INSERT16A(hit, v, id, vmax, d, p0 + e); }
      }
    }
    unsigned old = atomicMin(&tau[q], __float_as_uint(vmax));
    gate = fminf(vmax, __uint_as_float(old));
  }
  __syncthreads();
  const float gate0 = __uint_as_float(tau[q]);
  gate = fminf(gate, gate0);

  // ---- phase 2: certified window remainder, contiguous split across waves ----
  {
    float W = __builtin_sqrtf(gate0 + MG);
    float xl = qx - W, xr = qx + W;
#pragma unroll
    for (int o = 1; o < 64; o <<= 1) {
      xl = fminf(xl, __shfl_xor(xl, o));
      xr = fmaxf(xr, __shfl_xor(xr, o));
    }
    int bL = (int)((xl + 5.0f) * 25.6f); bL = bL < 0 ? 0 : (bL > 255 ? 255 : bL);
    int bR = (int)((xr + 5.0f) * 25.6f); bR = bR < 0 ? 0 : (bR > 255 ? 255 : bR);
    const int iL = __builtin_amdgcn_readfirstlane(offs[bL]);
    const int iRx = __builtin_amdgcn_readfirstlane(offs[bR + 1]);
    const int LL = max(0, base - iL);            // left remainder count
    const int LR = max(0, iRx - (base + SEED));  // right remainder count
    const int rem = LL + LR;
    const int cpw = (rem + 7) >> 3;              // per-wave share (ceil)
    const int k0 = j * cpw;
    const int k1 = min(k0 + cpw, rem);

    for (int k = k0; k < k1; k += 8) {
      if (__any(cnt > CAP - 8)) { FLUSH(); }
      float4 c[8]; int pp[8];
#pragma unroll
      for (int e = 0; e < 8; e++) {
        int kk = min(k + e, rem - 1);
        int p = (kk < LL) ? (iL + kk) : (base + SEED + (kk - LL));
        pp[e] = p;
        c[e] = pks[p];                           // wave-uniform s_loads
      }
#pragma unroll
      for (int e = 0; e < 8; e++) {
        DCALC(c[e], d)
        if ((k + e < k1) && (d < gate)) {
          poolF[lbase + cnt] = d;
          poolI[lbase + cnt] = (unsigned short)pp[e];
          cnt++;
        }
      }
    }
    FLUSH();
  }
  __syncthreads();  // scan buffers dead; merge overlay usable

  // ---- phase 3: merge tree (R7-verified shape) ----
  // stage A: odd waves publish; even wave j folds wave j+1
  if (j & 1) {
    const int s_ = j >> 1;
#pragma unroll
    for (int i = 0; i < KNN; i++) {
      Xd[(s_ * KNN + i) * QPB + q] = v[i];
      Xi[(s_ * KNN + i) * QPB + q] = (unsigned short)id[i];
    }
  }
  __syncthreads();
  if (!(j & 1)) {
    const int s_ = j >> 1;
    for (int ss = 0; ss < KNN; ss++) {
      float d = Xd[(s_ * KNN + ss) * QPB + q];
      bool hit = (d < vmax);
      if (__any(hit)) {
        int m_ = Xi[(s_ * KNN + ss) * QPB + q];
        INSERT16A(hit, v, id, vmax, d, m_);
      }
    }
  }
  __syncthreads();
  // stage B: waves 2,6 publish; waves 0,4 fold
  if (j == 2 || j == 6) {
    const int s_ = j >> 2;
#pragma unroll
    for (int i = 0; i < KNN; i++) {
      Xd[(s_ * KNN + i) * QPB + q] = v[i];
      Xi[(s_ * KNN + i) * QPB + q] = (unsigned short)id[i];
    }
  }
  __syncthreads();
  if (j == 0 || j == 4) {
    const int s_ = j >> 2;
    for (int ss = 0; ss < KNN; ss++) {
      float d = Xd[(s_ * KNN + ss) * QPB + q];
      bool hit = (d < vmax);
      if (__any(hit)) {
        int m_ = Xi[(s_ * KNN + ss) * QPB + q];
        INSERT16A(hit, v, id, vmax, d, m_);
      }
    }
  }
  __syncthreads();
  // stage C: wave 4 publishes; wave 0 folds -> final, translate + store
  if (j == 4) {
#pragma unroll
    for (int i = 0; i < KNN; i++) {
      Xd[i * QPB + q] = v[i];
      Xi[i * QPB + q] = (unsigned short)id[i];
    }
  }
  __syncthreads();
  if (j == 0) {
    for (int ss = 0; ss < KNN; ss++) {
      float d = Xd[ss * QPB + q];
      bool hit = (d < vmax);
      if (__any(hit)) {
        int m_ = Xi[ss * QPB + q];
        INSERT16A(hit, v, id, vmax, d, m_);
      }
    }
    const unsigned mq = sidx[s];
    float* ob = obase + mq;
#pragma unroll
    for (int r = 0; r < 8; r++) {
      unsigned i0 = (unsigned)sidx[id[2 * r] & (N_ - 1)];
      unsigned i1 = (unsigned)sidx[id[2 * r + 1] & (N_ - 1)];
      ob[(size_t)r * N_] = __uint_as_float(i0 | (i1 << 16));
    }
  }
}

// ---------------- K_fe: gather + fe + shortcut GEMM (R8/R9-verified) ----------
__global__ __launch_bounds__(NTHR, 2) void k_fe(
    const float4* __restrict__ pk, const float4* __restrict__ prm,
    const float* __restrict__ feature, const float* __restrict__ wsM,
    const float* __restrict__ bs, float* __restrict__ out) {
  const int blk = blockIdx.x;
  const int b  = blk / BLOCKS_PER_B;
  const int n0 = (blk % BLOCKS_PER_B) * QPB;
  const int t = threadIdx.x;
  const int q = t & 63;
  const int j = __builtin_amdgcn_readfirstlane(t >> 6);
  const size_t bb = (size_t)b << 13;
  const float INF = __uint_as_float(0x7f800000u);

  __shared__ float4 prmL[2 * HDIM];
  __shared__ float gp[4 * KNN * QPB];
  __shared__ float feL[DIN * QPB];
  __shared__ alignas(16) float wsL[DOUT * DIN];

  for (int i = t; i < 2 * HDIM; i += NTHR) prmL[i] = prm[i];
  for (int i = t; i < DOUT * DIN / 4; i += NTHR)
    ((float4*)wsL)[i] = ((const float4*)wsM)[i];
#pragma unroll
  for (int r = 0; r < 8; r++) {
    int c = j * 8 + r;
    feL[c * QPB + q] = feature[(size_t)(b * DIN + c) * N_ + n0 + q];
  }

  const float4 qv = pk[bb + n0 + q];
  const float qx = qv.x, qy = qv.y, qz = qv.z;

  float* ob = out + (size_t)b * DOUT * N_ + n0 + q;

  unsigned prb = __float_as_uint(ob[(size_t)j * N_]);
#pragma unroll
  for (int kk = 0; kk < 2; kk++) {
    int k = j * 2 + kk;
    int m = (int)((kk ? (prb >> 16) : prb) & 0xFFFFu) & (N_ - 1);
    float4 c = pk[bb + m];
    float dx = __fsub_rn(c.x, qx), dy = __fsub_rn(c.y, qy), dz = __fsub_rn(c.z, qz);
    float dsq = __fadd_rn(__fadd_rn(__fmul_rn(dx, dx), __fmul_rn(dy, dy)),
                          __fmul_rn(dz, dz));
    gp[k * QPB + q] = c.x;
    gp[(KNN + k) * QPB + q] = c.y;
    gp[(2 * KNN + k) * QPB + q] = c.z;
    gp[(3 * KNN + k) * QPB + q] = dsq;
  }
  __syncthreads();

  float fo[8];
  {
    float nx[KNN], ny[KNN], nz[KNN], nd[KNN];
#pragma unroll
    for (int k = 0; k < KNN; k++) {
      nx[k] = gp[k * QPB + q];
      ny[k] = gp[(KNN + k) * QPB + q];
      nz[k] = gp[(2 * KNN + k) * QPB + q];
      nd[k] = gp[(3 * KNN + k) * QPB + q];
    }
#pragma unroll
    for (int oi = 0; oi < 8; oi++) {
      int o = j * 8 + oi;
      float4 pA = prmL[o], pB = prmL[HDIM + o];
      float basev = fmaf(qz, pA.z, fmaf(qy, pA.y, fmaf(qx, pA.x, pA.w)));
      float mx = -INF;
#pragma unroll
      for (int k = 0; k < KNN; k++) {
        float tv = fmaf(nz[k], pB.z,
                   fmaf(ny[k], pB.y,
                   fmaf(nx[k], pB.x, __fmul_rn(nd[k], pB.w))));
        mx = fmaxf(mx, tv);
      }
      fo[oi] = basev + mx;
    }
  }

  float acc[16];
#pragma unroll
  for (int oi = 0; oi < 16; oi++) acc[oi] = 0.f;
  for (int c4 = 0; c4 < DIN / 4; c4++) {
    float f0 = feL[(4 * c4 + 0) * QPB + q];
    float f1 = feL[(4 * c4 + 1) * QPB + q];
    float f2 = feL[(4 * c4 + 2) * QPB + q];
    float f3 = feL[(4 * c4 + 3) * QPB + q];
#pragma unroll
    for (int oi = 0; oi < 16; oi++) {
      int o = (oi < 8) ? (j * 8 + oi) : (64 + j * 8 + oi - 8);
      float4 w = ((const float4*)(wsL + o * DIN))[c4];
      acc[oi] = fmaf(w.x, f0, acc[oi]);
      acc[oi] = fmaf(w.y, f1, acc[oi]);
      acc[oi] = fmaf(w.z, f2, acc[oi]);
      acc[oi] = fmaf(w.w, f3, acc[oi]);
    }
  }
#pragma unroll
  for (int oi = 0; oi < 16; oi++) {
    int o = (oi < 8) ? (j * 8 + oi) : (64 + j * 8 + oi - 8);
    ob[(size_t)o * N_] = acc[oi] + bs[o] + fo[oi & 7];
  }
}

extern "C" void kernel_launch(void* const* d_in, const int* in_sizes, int n_in,
                              void* d_out, int out_size, void* d_ws, size_t ws_size,
                              hipStream_t stream) {
  const float* xyz     = (const float*)d_in[0];
  const float* feature = (const float*)d_in[1];
  const float* w1 = (const float*)d_in[2];
  const float* b1 = (const float*)d_in[3];
  const float* w2 = (const float*)d_in[4];
  const float* b2 = (const float*)d_in[5];
  const float* w3 = (const float*)d_in[6];
  const float* b3 = (const float*)d_in[7];
  const float* wsM = (const float*)d_in[8];
  const float* bs  = (const float*)d_in[9];
  float* out = (float*)d_out;

  float4* prm = (float4*)d_ws;
  float4* pkB = (float4*)((char*)d_ws + 8192);

  for (int b = 0; b < B_; b++)
    hipMemsetAsync(out + (size_t)b * DOUT * N_ + 13 * (size_t)N_, 0, 512 * 4, stream);

  hipLaunchKernelGGL(k_prep, dim3(128), dim3(256), 0, stream,
                     xyz, w1, b1, w2, b2, w3, b3, pkB, prm, out);
  hipLaunchKernelGGL(k_scatter, dim3(128), dim3(256), 0, stream, pkB, out);
  hipLaunchKernelGGL(k_knn, dim3(B_ * BLOCKS_PER_B), dim3(NTHR), 0, stream, out);
  hipLaunchKernelGGL(k_fe, dim3(B_ * BLOCKS_PER_B), dim3(NTHR), 0, stream,
                     pkB, prm, feature, wsM, bs, out);
}

// Round 11
// 360.438 us; speedup vs baseline: 5.5634x; 1.0485x over previous
//
#include <hip/hip_runtime.h>

#define B_ 4
#define N_ 8192
#define DIN 64
#define HDIM 64
#define DOUT 128
#define KNN 16
#define QPB 64
#define NTHR 512
#define BLOCKS_PER_B (N_ / QPB)  // 128
#define MG 1e-3f                 // certified slack >> d-chain rounding (~5e-5)
#define NBKT 256
#define CAP 16                   // deferred-push slots per thread
#define CAPP 17                  // padded per-lane stride
#define SEED 768                 // total seed positions (8 waves x 96)

// out-row scratch layout per batch (obase = out + b*DOUT*N_):
//  rows 8..11 : pks float4[8192]  (bucket-x-sorted points, w = exact sq)
//  row 12     : sidx ushort[8192] (sorted pos -> original index)
//  row 13     : hist int[256] | cnt2 int[256] | offs int[257]

// ---------------- K_zero: zero hist+cnt2 for all batches (1 launch) -----------
__global__ __launch_bounds__(256) void k_zero(float* __restrict__ out) {
  int* p = (int*)(out + (size_t)blockIdx.x * DOUT * N_ + 13 * (size_t)N_);
  p[threadIdx.x] = 0;
  p[256 + threadIdx.x] = 0;
}

// ---------------- K_prep: pack (x,y,z,sq) + x-histogram + affine params -------
__global__ __launch_bounds__(256) void k_prep(
    const float* __restrict__ xyz,
    const float* __restrict__ w1, const float* __restrict__ b1,
    const float* __restrict__ w2, const float* __restrict__ b2,
    const float* __restrict__ w3, const float* __restrict__ b3,
    float4* __restrict__ pk, float4* __restrict__ prm, float* __restrict__ out) {
  const int blk = blockIdx.x, t = threadIdx.x;
  const int b = blk >> 5;
  const int m = ((blk & 31) << 8) + t;
  const float* xb = xyz + (size_t)b * 3 * N_;
  float x = xb[m], y = xb[N_ + m], z = xb[2 * N_ + m];
  float sq = __fadd_rn(__fadd_rn(__fmul_rn(x, x), __fmul_rn(y, y)), __fmul_rn(z, z));
  pk[((size_t)b << 13) + m] = make_float4(x, y, z, sq);

  __shared__ int histL[NBKT];
  histL[t] = 0;
  __syncthreads();
  int bi = (int)((x + 5.0f) * 25.6f);
  bi = bi < 0 ? 0 : (bi > 255 ? 255 : bi);
  atomicAdd(&histL[bi], 1);
  __syncthreads();
  {
    int* hist = (int*)(out + (size_t)b * DOUT * N_ + 13 * (size_t)N_);
    if (histL[t] > 0) atomicAdd(&hist[t], histL[t]);
  }

  if (blk == 0) {
    __shared__ float M2[HDIM][10];
    __shared__ float bb[HDIM];
    const int o = t;
    if (o < HDIM) {
      float r[10];
#pragma unroll
      for (int c = 0; c < 10; c++) r[c] = 0.f;
      float s = b2[o];
      for (int l = 0; l < HDIM; l++) {
        float w = w2[o * HDIM + l];
#pragma unroll
        for (int c = 0; c < 10; c++) r[c] = fmaf(w, w1[l * 10 + c], r[c]);
        s = fmaf(w, b1[l], s);
      }
#pragma unroll
      for (int c = 0; c < 10; c++) M2[o][c] = r[c];
      bb[o] = s;
    }
    __syncthreads();
    if (o < HDIM) {
      float r3[10];
#pragma unroll
      for (int c = 0; c < 10; c++) r3[c] = 0.f;
      float bc = b3[o];
      for (int l = 0; l < HDIM; l++) {
        float w = w3[o * HDIM + l];
#pragma unroll
        for (int c = 0; c < 10; c++) r3[c] = fmaf(w, M2[l][c], r3[c]);
        bc = fmaf(w, bb[l], bc);
      }
      prm[o]      = make_float4(r3[0] - r3[6], r3[1] - r3[7], r3[2] - r3[8], bc);
      prm[64 + o] = make_float4(r3[3] + r3[6], r3[4] + r3[7], r3[5] + r3[8], r3[9]);
    }
  }
}

// ---------------- K_scatter: counting-sort by x-bucket into out scratch -------
__global__ __launch_bounds__(256) void k_scatter(const float4* __restrict__ pk,
                                                 float* __restrict__ out) {
  const int blk = blockIdx.x, t = threadIdx.x;
  const int b = blk >> 5;
  const int m = ((blk & 31) << 8) + t;
  float* obase = out + (size_t)b * DOUT * N_;
  float4* pks = (float4*)(obase + 8 * (size_t)N_);
  unsigned short* sidx = (unsigned short*)(obase + 12 * (size_t)N_);
  int* hist = (int*)(obase + 13 * (size_t)N_);
  int* cnt2 = hist + NBKT;
  int* offs = hist + 2 * NBKT;

  __shared__ int histL[NBKT];
  __shared__ int offsL[NBKT + 1];
  histL[t] = hist[t];
  __syncthreads();
  if (t == 0) {
    int acc = 0;
    for (int i = 0; i < NBKT; i++) { offsL[i] = acc; acc += histL[i]; }
    offsL[NBKT] = acc;
  }
  __syncthreads();
  if ((blk & 31) == 0) {
    for (int i = t; i < NBKT + 1; i += 256) offs[i] = offsL[i];
  }
  float4 c = pk[((size_t)b << 13) + m];
  int bi = (int)((c.x + 5.0f) * 25.6f);
  bi = bi < 0 ? 0 : (bi > 255 ? 255 : bi);
  int pos = offsL[bi] + atomicAdd(&cnt2[bi], 1);
  pks[pos] = c;
  sidx[pos] = (unsigned short)m;
}

// max of 16 via v_max3-friendly triple nesting
#define MAX16(VARR, VMAX)                                                     \
  {                                                                           \
    float _m0 = fmaxf(fmaxf(VARR[0], VARR[1]), VARR[2]);                      \
    float _m1 = fmaxf(fmaxf(VARR[3], VARR[4]), VARR[5]);                      \
    float _m2 = fmaxf(fmaxf(VARR[6], VARR[7]), VARR[8]);                      \
    float _m3 = fmaxf(fmaxf(VARR[9], VARR[10]), VARR[11]);                    \
    float _m4 = fmaxf(fmaxf(VARR[12], VARR[13]), VARR[14]);                   \
    float _a = fmaxf(fmaxf(_m0, _m1), _m2);                                   \
    float _b = fmaxf(fmaxf(_m3, _m4), VARR[15]);                              \
    VMAX = fmaxf(_a, _b);                                                     \
  }

// replace-max insert (always-insert form, for FLUSH drains)
#define INSERT16(VARR, IARR, VMAX, DVAL, MIDX)                    \
  {                                                               \
    bool done = false;                                            \
    _Pragma("unroll") for (int _i = 0; _i < KNN; _i++) {          \
      bool hit = (!done) && (VARR[_i] == VMAX);                   \
      if (hit) { VARR[_i] = (DVAL); IARR[_i] = (MIDX); }          \
      done = done | hit;                                          \
    }                                                             \
    MAX16(VARR, VMAX);                                            \
  }

// per-lane predicated replace-max insert (ACC = this lane accepts)
#define INSERT16A(ACC, VARR, IARR, VMAX, DVAL, MIDX)              \
  {                                                               \
    bool done = !(ACC);                                           \
    _Pragma("unroll") for (int _i = 0; _i < KNN; _i++) {          \
      bool hit = (!done) && (VARR[_i] == VMAX);                   \
      if (hit) { VARR[_i] = (DVAL); IARR[_i] = (MIDX); }          \
      done = done | hit;                                          \
    }                                                             \
    MAX16(VARR, VMAX);                                            \
  }

// exact reference-rounded d: sq precomputed (c.w, bit-exact k_prep chain);
// d = fmaf(-2,dot,qs+cs) == (qs+cs) - 2*dot bit-exactly (2*dot exact in fp32)
#define DCALC(C, D)                                                           \
  float dot = fmaf((C).z, qz, fmaf((C).y, qy, __fmul_rn((C).x, qx)));         \
  float D = fmaf(-2.0f, dot, __fadd_rn(qs, (C).w));

// drain deferred (d,idx) buffer -- LDS only; publish tau via returned old value
#define FLUSH()                                                   \
  {                                                               \
    for (int c_ = 0; c_ < cnt; c_++) {                            \
      float fd_ = poolF[lbase + c_];                              \
      int fm_ = poolI[lbase + c_];                                \
      if (fd_ < vmax) { INSERT16(v, id, vmax, fd_, fm_); }        \
    }                                                             \
    cnt = 0;                                                      \
    unsigned old_ = atomicMin(&tau[q], __float_as_uint(vmax));    \
    gate = fminf(vmax, __uint_as_float(old_));                    \
  }

// one 8-candidate deferred-push batch from wave-uniform regs (R4 idiom)
#define PROC8P(CARR, PARR, LIM, KBASE)                                        \
  {                                                                           \
    if (__any(cnt > CAP - 8)) { FLUSH(); }                                    \
    _Pragma("unroll") for (int e = 0; e < 8; e++) {                           \
      DCALC(CARR[e], d_)                                                      \
      if (((KBASE) + e < (LIM)) && (d_ < gate)) {                             \
        poolF[lbase + cnt] = d_;                                              \
        poolI[lbase + cnt] = (unsigned short)PARR[e];                         \
        cnt++;                                                                \
      }                                                                       \
    }                                                                         \
  }

// ---------------- K_knn: champion engine (R4 idiom) over certified window -----
// block g: 64 bucket-sorted queries s=s0+q, 8 waves. Phase A: wave j runs the
// R4-proven engine on its 96-seed segment: warm-start direct fill (16, zero
// insert cost) then deferred-push batches + FLUSH -> tau[q] = certified d16
// upper bound. Phase B: certified bucket window (|dx| <= sqrt(tau+MG)) from
// offs[]. Phase C: remainder split contiguously across waves, same deferred-
// push engine. Phase D: R7/R10-proven merge tree + sidx translation.
__global__ __launch_bounds__(NTHR, 4) void k_knn(float* __restrict__ out) {
  const int blk = blockIdx.x;
  const int b = blk >> 7;
  const int g = blk & 127;
  const int s0 = g * QPB;
  const int t = threadIdx.x;
  const int q = t & 63;
  const int j = __builtin_amdgcn_readfirstlane(t >> 6);
  const int lbase = t * CAPP;
  float* obase = out + (size_t)b * DOUT * N_;
  const float4* pks = (const float4*)(obase + 8 * (size_t)N_);
  const unsigned short* sidx = (const unsigned short*)(obase + 12 * (size_t)N_);
  const int* offs = (const int*)(obase + 13 * (size_t)N_) + 2 * NBKT;

  __shared__ unsigned tau[QPB];
  __shared__ alignas(16) float poolF[CAPP * NTHR];          // 34.8 KB
  __shared__ alignas(16) unsigned short poolI[CAPP * NTHR]; // 17.4 KB
  float* Xd = poolF;                 // merge overlay [128][64] f32 (32KB)
  unsigned short* Xi = poolI;        // merge overlay [128][64] u16 (16KB)

  if (t < QPB) tau[t] = 0x7f800000u;

  const int s = s0 + q;
  const float4 qv = pks[s];
  const float qx = qv.x, qy = qv.y, qz = qv.z, qs = qv.w;

  const float INF = __uint_as_float(0x7f800000u);
  float v[KNN]; int id[KNN];
  float vmax, gate;
  int cnt = 0;
  __syncthreads();

  // ---- phase A: seed segment, champion engine ----
  const int base = min(max(s0 - 352, 0), N_ - SEED);
  const int segb = base + j * 96;
  {
    // warm start: direct fill of all 16 slots (no INSERT cost)
    float4 c[KNN];
#pragma unroll
    for (int e = 0; e < KNN; e++) c[e] = pks[segb + e];
#pragma unroll
    for (int e = 0; e < KNN; e++) {
      DCALC(c[e], d)
      v[e] = d;
      id[e] = segb + e;
    }
    MAX16(v, vmax);
    unsigned old = atomicMin(&tau[q], __float_as_uint(vmax));
    gate = fminf(vmax, __uint_as_float(old));
    // remaining 80 seeds: deferred-push batches
    for (int u0 = KNN; u0 < 96; u0 += 8) {
      float4 cc[8]; int pp[8];
#pragma unroll
      for (int e = 0; e < 8; e++) { pp[e] = segb + u0 + e; cc[e] = pks[pp[e]]; }
      PROC8P(cc, pp, 96 + segb, segb + u0)  // limit in absolute terms
    }
    FLUSH();
  }
  __syncthreads();
  const float gate0 = __uint_as_float(tau[q]);
  gate = fminf(gate, gate0);

  // ---- phase B: certified window from bucket offsets ----
  float W = __builtin_sqrtf(gate0 + MG);
  float xl = qx - W, xr = qx + W;
#pragma unroll
  for (int o = 1; o < 64; o <<= 1) {
    xl = fminf(xl, __shfl_xor(xl, o));
    xr = fmaxf(xr, __shfl_xor(xr, o));
  }
  int bL = (int)((xl + 5.0f) * 25.6f); bL = bL < 0 ? 0 : (bL > 255 ? 255 : bL);
  int bR = (int)((xr + 5.0f) * 25.6f); bR = bR < 0 ? 0 : (bR > 255 ? 255 : bR);
  const int iL = __builtin_amdgcn_readfirstlane(offs[bL]);
  const int iRx = __builtin_amdgcn_readfirstlane(offs[bR + 1]);
  const int LL = max(0, base - iL);            // left remainder count
  const int LR = max(0, iRx - (base + SEED));  // right remainder count
  const int rem = LL + LR;
  const int cpw = (rem + 7) >> 3;
  const int k0 = j * cpw;
  const int k1 = min(k0 + cpw, rem);

  // ---- phase C: remainder scan, champion engine ----
  for (int k = k0; k < k1; k += 8) {
    float4 cc[8]; int pp[8];
#pragma unroll
    for (int e = 0; e < 8; e++) {
      int kk = min(k + e, rem - 1);
      int p = (kk < LL) ? (iL + kk) : (base + SEED + (kk - LL));
      pp[e] = p;
      cc[e] = pks[p];
    }
    PROC8P(cc, pp, k1, k)
  }
  FLUSH();
  __syncthreads();  // scan buffers dead; merge overlay usable

  // ---- phase D: merge tree (R7/R10-verified) ----
  if (j & 1) {
    const int s_ = j >> 1;
#pragma unroll
    for (int i = 0; i < KNN; i++) {
      Xd[(s_ * KNN + i) * QPB + q] = v[i];
      Xi[(s_ * KNN + i) * QPB + q] = (unsigned short)id[i];
    }
  }
  __syncthreads();
  if (!(j & 1)) {
    const int s_ = j >> 1;
    for (int ss = 0; ss < KNN; ss++) {
      float d = Xd[(s_ * KNN + ss) * QPB + q];
      bool hit = (d < vmax);
      if (__any(hit)) {
        int m_ = Xi[(s_ * KNN + ss) * QPB + q];
        INSERT16A(hit, v, id, vmax, d, m_);
      }
    }
  }
  __syncthreads();
  if (j == 2 || j == 6) {
    const int s_ = j >> 2;
#pragma unroll
    for (int i = 0; i < KNN; i++) {
      Xd[(s_ * KNN + i) * QPB + q] = v[i];
      Xi[(s_ * KNN + i) * QPB + q] = (unsigned short)id[i];
    }
  }
  __syncthreads();
  if (j == 0 || j == 4) {
    const int s_ = j >> 2;
    for (int ss = 0; ss < KNN; ss++) {
      float d = Xd[(s_ * KNN + ss) * QPB + q];
      bool hit = (d < vmax);
      if (__any(hit)) {
        int m_ = Xi[(s_ * KNN + ss) * QPB + q];
        INSERT16A(hit, v, id, vmax, d, m_);
      }
    }
  }
  __syncthreads();
  if (j == 4) {
#pragma unroll
    for (int i = 0; i < KNN; i++) {
      Xd[i * QPB + q] = v[i];
      Xi[i * QPB + q] = (unsigned short)id[i];
    }
  }
  __syncthreads();
  if (j == 0) {
    for (int ss = 0; ss < KNN; ss++) {
      float d = Xd[ss * QPB + q];
      bool hit = (d < vmax);
      if (__any(hit)) {
        int m_ = Xi[ss * QPB + q];
        INSERT16A(hit, v, id, vmax, d, m_);
      }
    }
    const unsigned mq = sidx[s];
    float* ob = obase + mq;
#pragma unroll
    for (int r = 0; r < 8; r++) {
      unsigned i0 = (unsigned)sidx[id[2 * r] & (N_ - 1)];
      unsigned i1 = (unsigned)sidx[id[2 * r + 1] & (N_ - 1)];
      ob[(size_t)r * N_] = __uint_as_float(i0 | (i1 << 16));
    }
  }
}

// ---------------- K_fe: gather + fe + shortcut GEMM (R8/R9/R10-verified) ------
__global__ __launch_bounds__(NTHR, 2) void k_fe(
    const float4* __restrict__ pk, const float4* __restrict__ prm,
    const float* __restrict__ feature, const float* __restrict__ wsM,
    const float* __restrict__ bs, float* __restrict__ out) {
  const int blk = blockIdx.x;
  const int b  = blk / BLOCKS_PER_B;
  const int n0 = (blk % BLOCKS_PER_B) * QPB;
  const int t = threadIdx.x;
  const int q = t & 63;
  const int j = __builtin_amdgcn_readfirstlane(t >> 6);
  const size_t bb = (size_t)b << 13;
  const float INF = __uint_as_float(0x7f800000u);

  __shared__ float4 prmL[2 * HDIM];
  __shared__ float gp[4 * KNN * QPB];
  __shared__ float feL[DIN * QPB];
  __shared__ alignas(16) float wsL[DOUT * DIN];

  for (int i = t; i < 2 * HDIM; i += NTHR) prmL[i] = prm[i];
  for (int i = t; i < DOUT * DIN / 4; i += NTHR)
    ((float4*)wsL)[i] = ((const float4*)wsM)[i];
#pragma unroll
  for (int r = 0; r < 8; r++) {
    int c = j * 8 + r;
    feL[c * QPB + q] = feature[(size_t)(b * DIN + c) * N_ + n0 + q];
  }

  const float4 qv = pk[bb + n0 + q];
  const float qx = qv.x, qy = qv.y, qz = qv.z;

  float* ob = out + (size_t)b * DOUT * N_ + n0 + q;

  unsigned prb = __float_as_uint(ob[(size_t)j * N_]);
#pragma unroll
  for (int kk = 0; kk < 2; kk++) {
    int k = j * 2 + kk;
    int m = (int)((kk ? (prb >> 16) : prb) & 0xFFFFu) & (N_ - 1);
    float4 c = pk[bb + m];
    float dx = __fsub_rn(c.x, qx), dy = __fsub_rn(c.y, qy), dz = __fsub_rn(c.z, qz);
    float dsq = __fadd_rn(__fadd_rn(__fmul_rn(dx, dx), __fmul_rn(dy, dy)),
                          __fmul_rn(dz, dz));
    gp[k * QPB + q] = c.x;
    gp[(KNN + k) * QPB + q] = c.y;
    gp[(2 * KNN + k) * QPB + q] = c.z;
    gp[(3 * KNN + k) * QPB + q] = dsq;
  }
  __syncthreads();

  float fo[8];
  {
    float nx[KNN], ny[KNN], nz[KNN], nd[KNN];
#pragma unroll
    for (int k = 0; k < KNN; k++) {
      nx[k] = gp[k * QPB + q];
      ny[k] = gp[(KNN + k) * QPB + q];
      nz[k] = gp[(2 * KNN + k) * QPB + q];
      nd[k] = gp[(3 * KNN + k) * QPB + q];
    }
#pragma unroll
    for (int oi = 0; oi < 8; oi++) {
      int o = j * 8 + oi;
      float4 pA = prmL[o], pB = prmL[HDIM + o];
      float basev = fmaf(qz, pA.z, fmaf(qy, pA.y, fmaf(qx, pA.x, pA.w)));
      float mx = -INF;
#pragma unroll
      for (int k = 0; k < KNN; k++) {
        float tv = fmaf(nz[k], pB.z,
                   fmaf(ny[k], pB.y,
                   fmaf(nx[k], pB.x, __fmul_rn(nd[k], pB.w))));
        mx = fmaxf(mx, tv);
      }
      fo[oi] = basev + mx;
    }
  }

  float acc[16];
#pragma unroll
  for (int oi = 0; oi < 16; oi++) acc[oi] = 0.f;
  for (int c4 = 0; c4 < DIN / 4; c4++) {
    float f0 = feL[(4 * c4 + 0) * QPB + q];
    float f1 = feL[(4 * c4 + 1) * QPB + q];
    float f2 = feL[(4 * c4 + 2) * QPB + q];
    float f3 = feL[(4 * c4 + 3) * QPB + q];
#pragma unroll
    for (int oi = 0; oi < 16; oi++) {
      int o = (oi < 8) ? (j * 8 + oi) : (64 + j * 8 + oi - 8);
      float4 w = ((const float4*)(wsL + o * DIN))[c4];
      acc[oi] = fmaf(w.x, f0, acc[oi]);
      acc[oi] = fmaf(w.y, f1, acc[oi]);
      acc[oi] = fmaf(w.z, f2, acc[oi]);
      acc[oi] = fmaf(w.w, f3, acc[oi]);
    }
  }
#pragma unroll
  for (int oi = 0; oi < 16; oi++) {
    int o = (oi < 8) ? (j * 8 + oi) : (64 + j * 8 + oi - 8);
    ob[(size_t)o * N_] = acc[oi] + bs[o] + fo[oi & 7];
  }
}

extern "C" void kernel_launch(void* const* d_in, const int* in_sizes, int n_in,
                              void* d_out, int out_size, void* d_ws, size_t ws_size,
                              hipStream_t stream) {
  const float* xyz     = (const float*)d_in[0];
  const float* feature = (const float*)d_in[1];
  const float* w1 = (const float*)d_in[2];
  const float* b1 = (const float*)d_in[3];
  const float* w2 = (const float*)d_in[4];
  const float* b2 = (const float*)d_in[5];
  const float* w3 = (const float*)d_in[6];
  const float* b3 = (const float*)d_in[7];
  const float* wsM = (const float*)d_in[8];
  const float* bs  = (const float*)d_in[9];
  float* out = (float*)d_out;

  float4* prm = (float4*)d_ws;
  float4* pkB = (float4*)((char*)d_ws + 8192);

  hipLaunchKernelGGL(k_zero, dim3(B_), dim3(256), 0, stream, out);
  hipLaunchKernelGGL(k_prep, dim3(128), dim3(256), 0, stream,
                     xyz, w1, b1, w2, b2, w3, b3, pkB, prm, out);
  hipLaunchKernelGGL(k_scatter, dim3(128), dim3(256), 0, stream, pkB, out);
  hipLaunchKernelGGL(k_knn, dim3(B_ * BLOCKS_PER_B), dim3(NTHR), 0, stream, out);
  hipLaunchKernelGGL(k_fe, dim3(B_ * BLOCKS_PER_B), dim3(NTHR), 0, stream,
                     pkB, prm, feature, wsM, bs, out);
}

// Round 12
// 350.918 us; speedup vs baseline: 5.7144x; 1.0271x over previous
//
#include <hip/hip_runtime.h>

#define B_ 4
#define N_ 8192
#define DIN 64
#define HDIM 64
#define DOUT 128
#define KNN 16
#define QPB 64
#define NTHR 512
#define BLOCKS_PER_B (N_ / QPB)  // 128
#define MG 1e-3f                 // certified slack >> d-chain rounding (~5e-5)
#define NBKT 256
#define CAP 16                   // deferred-push slots per thread
#define CAPP 17                  // padded per-lane stride
#define SEED 768                 // total seed positions (8 waves x 96)

// out-row scratch layout per batch (obase = out + b*DOUT*N_):
//  rows 8..11 : pks float4[8192]  (bucket-x-sorted points, w = exact sq)
//  row 12     : sidx ushort[8192] (sorted pos -> original index)
//  row 13     : hist int[256] | cnt2 int[256] | offs int[257]
//  row 14     : tau (merged-seed 16th distance, f32, keyed by sorted pos)
//  rows 16..31: merged seed list d[16]        (keyed by sorted pos)
//  rows 32..39: merged seed list pos pairs    (keyed by sorted pos)
//  rows 0..7  : FINAL ids packed (keyed by original idx; written by k_expand)

// ---------------- K_zero ------------------------------------------------------
__global__ __launch_bounds__(256) void k_zero(float* __restrict__ out) {
  int* p = (int*)(out + (size_t)blockIdx.x * DOUT * N_ + 13 * (size_t)N_);
  p[threadIdx.x] = 0;
  p[256 + threadIdx.x] = 0;
}

// ---------------- K_prep: pack (x,y,z,sq) + x-histogram + affine params -------
__global__ __launch_bounds__(256) void k_prep(
    const float* __restrict__ xyz,
    const float* __restrict__ w1, const float* __restrict__ b1,
    const float* __restrict__ w2, const float* __restrict__ b2,
    const float* __restrict__ w3, const float* __restrict__ b3,
    float4* __restrict__ pk, float4* __restrict__ prm, float* __restrict__ out) {
  const int blk = blockIdx.x, t = threadIdx.x;
  const int b = blk >> 5;
  const int m = ((blk & 31) << 8) + t;
  const float* xb = xyz + (size_t)b * 3 * N_;
  float x = xb[m], y = xb[N_ + m], z = xb[2 * N_ + m];
  float sq = __fadd_rn(__fadd_rn(__fmul_rn(x, x), __fmul_rn(y, y)), __fmul_rn(z, z));
  pk[((size_t)b << 13) + m] = make_float4(x, y, z, sq);

  __shared__ int histL[NBKT];
  histL[t] = 0;
  __syncthreads();
  int bi = (int)((x + 5.0f) * 25.6f);
  bi = bi < 0 ? 0 : (bi > 255 ? 255 : bi);
  atomicAdd(&histL[bi], 1);
  __syncthreads();
  {
    int* hist = (int*)(out + (size_t)b * DOUT * N_ + 13 * (size_t)N_);
    if (histL[t] > 0) atomicAdd(&hist[t], histL[t]);
  }

  if (blk == 0) {
    __shared__ float M2[HDIM][10];
    __shared__ float bb[HDIM];
    const int o = t;
    if (o < HDIM) {
      float r[10];
#pragma unroll
      for (int c = 0; c < 10; c++) r[c] = 0.f;
      float s = b2[o];
      for (int l = 0; l < HDIM; l++) {
        float w = w2[o * HDIM + l];
#pragma unroll
        for (int c = 0; c < 10; c++) r[c] = fmaf(w, w1[l * 10 + c], r[c]);
        s = fmaf(w, b1[l], s);
      }
#pragma unroll
      for (int c = 0; c < 10; c++) M2[o][c] = r[c];
      bb[o] = s;
    }
    __syncthreads();
    if (o < HDIM) {
      float r3[10];
#pragma unroll
      for (int c = 0; c < 10; c++) r3[c] = 0.f;
      float bc = b3[o];
      for (int l = 0; l < HDIM; l++) {
        float w = w3[o * HDIM + l];
#pragma unroll
        for (int c = 0; c < 10; c++) r3[c] = fmaf(w, M2[l][c], r3[c]);
        bc = fmaf(w, bb[l], bc);
      }
      prm[o]      = make_float4(r3[0] - r3[6], r3[1] - r3[7], r3[2] - r3[8], bc);
      prm[64 + o] = make_float4(r3[3] + r3[6], r3[4] + r3[7], r3[5] + r3[8], r3[9]);
    }
  }
}

// ---------------- K_scatter: counting-sort by x-bucket into out scratch -------
__global__ __launch_bounds__(256) void k_scatter(const float4* __restrict__ pk,
                                                 float* __restrict__ out) {
  const int blk = blockIdx.x, t = threadIdx.x;
  const int b = blk >> 5;
  const int m = ((blk & 31) << 8) + t;
  float* obase = out + (size_t)b * DOUT * N_;
  float4* pks = (float4*)(obase + 8 * (size_t)N_);
  unsigned short* sidx = (unsigned short*)(obase + 12 * (size_t)N_);
  int* hist = (int*)(obase + 13 * (size_t)N_);
  int* cnt2 = hist + NBKT;
  int* offs = hist + 2 * NBKT;

  __shared__ int histL[NBKT];
  __shared__ int offsL[NBKT + 1];
  histL[t] = hist[t];
  __syncthreads();
  if (t == 0) {
    int acc = 0;
    for (int i = 0; i < NBKT; i++) { offsL[i] = acc; acc += histL[i]; }
    offsL[NBKT] = acc;
  }
  __syncthreads();
  if ((blk & 31) == 0) {
    for (int i = t; i < NBKT + 1; i += 256) offs[i] = offsL[i];
  }
  float4 c = pk[((size_t)b << 13) + m];
  int bi = (int)((c.x + 5.0f) * 25.6f);
  bi = bi < 0 ? 0 : (bi > 255 ? 255 : bi);
  int pos = offsL[bi] + atomicAdd(&cnt2[bi], 1);
  pks[pos] = c;
  sidx[pos] = (unsigned short)m;
}

// max of 16 via v_max3-friendly triple nesting
#define MAX16(VARR, VMAX)                                                     \
  {                                                                           \
    float _m0 = fmaxf(fmaxf(VARR[0], VARR[1]), VARR[2]);                      \
    float _m1 = fmaxf(fmaxf(VARR[3], VARR[4]), VARR[5]);                      \
    float _m2 = fmaxf(fmaxf(VARR[6], VARR[7]), VARR[8]);                      \
    float _m3 = fmaxf(fmaxf(VARR[9], VARR[10]), VARR[11]);                    \
    float _m4 = fmaxf(fmaxf(VARR[12], VARR[13]), VARR[14]);                   \
    float _a = fmaxf(fmaxf(_m0, _m1), _m2);                                   \
    float _b = fmaxf(fmaxf(_m3, _m4), VARR[15]);                              \
    VMAX = fmaxf(_a, _b);                                                     \
  }

#define INSERT16(VARR, IARR, VMAX, DVAL, MIDX)                    \
  {                                                               \
    bool done = false;                                            \
    _Pragma("unroll") for (int _i = 0; _i < KNN; _i++) {          \
      bool hit = (!done) && (VARR[_i] == VMAX);                   \
      if (hit) { VARR[_i] = (DVAL); IARR[_i] = (MIDX); }          \
      done = done | hit;                                          \
    }                                                             \
    MAX16(VARR, VMAX);                                            \
  }

#define INSERT16A(ACC, VARR, IARR, VMAX, DVAL, MIDX)              \
  {                                                               \
    bool done = !(ACC);                                           \
    _Pragma("unroll") for (int _i = 0; _i < KNN; _i++) {          \
      bool hit = (!done) && (VARR[_i] == VMAX);                   \
      if (hit) { VARR[_i] = (DVAL); IARR[_i] = (MIDX); }          \
      done = done | hit;                                          \
    }                                                             \
    MAX16(VARR, VMAX);                                            \
  }

// exact reference-rounded d (sq precomputed in c.w, bit-exact k_prep chain)
#define DCALC(C, D)                                                           \
  float dot = fmaf((C).z, qz, fmaf((C).y, qy, __fmul_rn((C).x, qx)));         \
  float D = fmaf(-2.0f, dot, __fadd_rn(qs, (C).w));

#define FLUSH()                                                   \
  {                                                               \
    for (int c_ = 0; c_ < cnt; c_++) {                            \
      float fd_ = poolF[lbase + c_];                              \
      int fm_ = poolI[lbase + c_];                                \
      if (fd_ < vmax) { INSERT16(v, id, vmax, fd_, fm_); }        \
    }                                                             \
    cnt = 0;                                                      \
    unsigned old_ = atomicMin(&tau[q], __float_as_uint(vmax));    \
    gate = fminf(vmax, __uint_as_float(old_));                    \
  }

#define PROC8P(CARR, PARR, LIM, KBASE)                                        \
  {                                                                           \
    if (__any(cnt > CAP - 8)) { FLUSH(); }                                    \
    _Pragma("unroll") for (int e = 0; e < 8; e++) {                           \
      DCALC(CARR[e], d_)                                                      \
      if (((KBASE) + e < (LIM)) && (d_ < gate)) {                             \
        poolF[lbase + cnt] = d_;                                              \
        poolI[lbase + cnt] = (unsigned short)PARR[e];                         \
        cnt++;                                                                \
      }                                                                       \
    }                                                                         \
  }

// merge tree stages (R11-verified shape), shared by k_seed / k_expand
#define MERGE_TREE()                                                          \
  if (j & 1) {                                                                \
    const int s_ = j >> 1;                                                    \
    _Pragma("unroll") for (int i = 0; i < KNN; i++) {                         \
      Xd[(s_ * KNN + i) * QPB + q] = v[i];                                    \
      Xi[(s_ * KNN + i) * QPB + q] = (unsigned short)id[i];                   \
    }                                                                         \
  }                                                                           \
  __syncthreads();                                                            \
  if (!(j & 1)) {                                                             \
    const int s_ = j >> 1;                                                    \
    for (int ss = 0; ss < KNN; ss++) {                                        \
      float d = Xd[(s_ * KNN + ss) * QPB + q];                                \
      bool hit = (d < vmax);                                                  \
      if (__any(hit)) {                                                       \
        int m_ = Xi[(s_ * KNN + ss) * QPB + q];                               \
        INSERT16A(hit, v, id, vmax, d, m_);                                   \
      }                                                                       \
    }                                                                         \
  }                                                                           \
  __syncthreads();                                                            \
  if (j == 2 || j == 6) {                                                     \
    const int s_ = j >> 2;                                                    \
    _Pragma("unroll") for (int i = 0; i < KNN; i++) {                         \
      Xd[(s_ * KNN + i) * QPB + q] = v[i];                                    \
      Xi[(s_ * KNN + i) * QPB + q] = (unsigned short)id[i];                   \
    }                                                                         \
  }                                                                           \
  __syncthreads();                                                            \
  if (j == 0 || j == 4) {                                                     \
    const int s_ = j >> 2;                                                    \
    for (int ss = 0; ss < KNN; ss++) {                                        \
      float d = Xd[(s_ * KNN + ss) * QPB + q];                                \
      bool hit = (d < vmax);                                                  \
      if (__any(hit)) {                                                       \
        int m_ = Xi[(s_ * KNN + ss) * QPB + q];                               \
        INSERT16A(hit, v, id, vmax, d, m_);                                   \
      }                                                                       \
    }                                                                         \
  }                                                                           \
  __syncthreads();                                                            \
  if (j == 4) {                                                               \
    _Pragma("unroll") for (int i = 0; i < KNN; i++) {                         \
      Xd[i * QPB + q] = v[i];                                                 \
      Xi[i * QPB + q] = (unsigned short)id[i];                                \
    }                                                                         \
  }                                                                           \
  __syncthreads();                                                            \
  if (j == 0) {                                                               \
    for (int ss = 0; ss < KNN; ss++) {                                        \
      float d = Xd[ss * QPB + q];                                             \
      bool hit = (d < vmax);                                                  \
      if (__any(hit)) {                                                       \
        int m_ = Xi[ss * QPB + q];                                            \
        INSERT16A(hit, v, id, vmax, d, m_);                                   \
      }                                                                       \
    }                                                                         \
  }

// ---------------- K_seed: disjoint per-wave seeds + FULL merge -> tight tau ---
// Merging all 768 seeds gives vmax0 = 16th-of-768 (r^2 ~ 1/24 central), ~8x
// tighter than R11's min-of-per-wave bound (~1/3) -> the certified window
// shrinks ~2.8x and expansion pushes nearly vanish. Wave0 stores the merged
// list (d rows 16..31, pos-pair rows 32..39) + tau (row 14), keyed by sorted s.
__global__ __launch_bounds__(NTHR, 4) void k_seed(float* __restrict__ out) {
  const int blk = blockIdx.x;
  const int b = blk >> 7;
  const int g = blk & 127;
  const int s0 = g * QPB;
  const int t = threadIdx.x;
  const int q = t & 63;
  const int j = __builtin_amdgcn_readfirstlane(t >> 6);
  const int lbase = t * CAPP;
  float* obase = out + (size_t)b * DOUT * N_;
  const float4* pks = (const float4*)(obase + 8 * (size_t)N_);

  __shared__ unsigned tau[QPB];
  __shared__ alignas(16) float poolF[CAPP * NTHR];
  __shared__ alignas(16) unsigned short poolI[CAPP * NTHR];
  float* Xd = poolF;
  unsigned short* Xi = poolI;

  if (t < QPB) tau[t] = 0x7f800000u;

  const int s = s0 + q;
  const float4 qv = pks[s];
  const float qx = qv.x, qy = qv.y, qz = qv.z, qs = qv.w;

  float v[KNN]; int id[KNN];
  float vmax, gate;
  int cnt = 0;
  __syncthreads();

  const int base = min(max(s0 - 352, 0), N_ - SEED);
  const int segb = base + j * 96;
  {
    float4 c[KNN];
#pragma unroll
    for (int e = 0; e < KNN; e++) c[e] = pks[segb + e];
#pragma unroll
    for (int e = 0; e < KNN; e++) {
      DCALC(c[e], d)
      v[e] = d;
      id[e] = segb + e;
    }
    MAX16(v, vmax);
    unsigned old = atomicMin(&tau[q], __float_as_uint(vmax));
    gate = fminf(vmax, __uint_as_float(old));
    for (int u0 = KNN; u0 < 96; u0 += 8) {
      float4 cc[8]; int pp[8];
#pragma unroll
      for (int e = 0; e < 8; e++) { pp[e] = segb + u0 + e; cc[e] = pks[pp[e]]; }
      PROC8P(cc, pp, segb + 96, segb + u0)
    }
    FLUSH();
  }
  __syncthreads();  // scan buffers dead; merge overlay usable

  MERGE_TREE()

  if (j == 0) {
    obase[14 * (size_t)N_ + s] = vmax;
#pragma unroll
    for (int i = 0; i < KNN; i++) obase[(size_t)(16 + i) * N_ + s] = v[i];
#pragma unroll
    for (int r = 0; r < 8; r++) {
      unsigned p0 = (unsigned)id[2 * r] & 0xFFFFu;
      unsigned p1 = (unsigned)id[2 * r + 1] & 0xFFFFu;
      obase[(size_t)(32 + r) * N_ + s] = __uint_as_float(p0 | (p1 << 16));
    }
  }
}

// ---------------- K_expand: tight certified window scan + merge + store -------
__global__ __launch_bounds__(NTHR, 4) void k_expand(float* __restrict__ out) {
  const int blk = blockIdx.x;
  const int b = blk >> 7;
  const int g = blk & 127;
  const int s0 = g * QPB;
  const int t = threadIdx.x;
  const int q = t & 63;
  const int j = __builtin_amdgcn_readfirstlane(t >> 6);
  const int lbase = t * CAPP;
  float* obase = out + (size_t)b * DOUT * N_;
  const float4* pks = (const float4*)(obase + 8 * (size_t)N_);
  const unsigned short* sidx = (const unsigned short*)(obase + 12 * (size_t)N_);
  const int* offs = (const int*)(obase + 13 * (size_t)N_) + 2 * NBKT;

  __shared__ unsigned tau[QPB];
  __shared__ alignas(16) float poolF[CAPP * NTHR];
  __shared__ alignas(16) unsigned short poolI[CAPP * NTHR];
  float* Xd = poolF;
  unsigned short* Xi = poolI;

  const int s = s0 + q;
  const float4 qv = pks[s];
  const float qx = qv.x, qy = qv.y, qz = qv.z, qs = qv.w;

  const float INF = __uint_as_float(0x7f800000u);
  const float g0 = obase[14 * (size_t)N_ + s];  // merged-seed tau (tight)
  if (t < QPB) tau[t] = __float_as_uint(g0);    // wave0 lanes: q==t

  float v[KNN]; int id[KNN];
  float vmax, gate;
  int cnt = 0;
  if (j == 0) {
    // wave0 resumes with the merged seed list
#pragma unroll
    for (int i = 0; i < KNN; i++) v[i] = obase[(size_t)(16 + i) * N_ + s];
#pragma unroll
    for (int r = 0; r < 8; r++) {
      unsigned pv = __float_as_uint(obase[(size_t)(32 + r) * N_ + s]);
      id[2 * r] = (int)(pv & 0xFFFFu);
      id[2 * r + 1] = (int)(pv >> 16);
    }
    MAX16(v, vmax);
  } else {
#pragma unroll
    for (int i = 0; i < KNN; i++) { v[i] = INF; id[i] = 0; }
    vmax = INF;
  }
  gate = fminf(vmax, g0);
  __syncthreads();

  // certified window from bucket offsets
  float W = __builtin_sqrtf(g0 + MG);
  float xl = qx - W, xr = qx + W;
#pragma unroll
  for (int o = 1; o < 64; o <<= 1) {
    xl = fminf(xl, __shfl_xor(xl, o));
    xr = fmaxf(xr, __shfl_xor(xr, o));
  }
  int bL = (int)((xl + 5.0f) * 25.6f); bL = bL < 0 ? 0 : (bL > 255 ? 255 : bL);
  int bR = (int)((xr + 5.0f) * 25.6f); bR = bR < 0 ? 0 : (bR > 255 ? 255 : bR);
  const int iL = __builtin_amdgcn_readfirstlane(offs[bL]);
  const int iRx = __builtin_amdgcn_readfirstlane(offs[bR + 1]);
  const int base = min(max(s0 - 352, 0), N_ - SEED);
  const int LL = max(0, base - iL);
  const int LR = max(0, iRx - (base + SEED));
  const int rem = LL + LR;
  const int cpw = (rem + 7) >> 3;
  const int k0 = j * cpw;
  const int k1 = min(k0 + cpw, rem);

  for (int k = k0; k < k1; k += 8) {
    float4 cc[8]; int pp[8];
#pragma unroll
    for (int e = 0; e < 8; e++) {
      int kk = min(k + e, rem - 1);
      int p = (kk < LL) ? (iL + kk) : (base + SEED + (kk - LL));
      pp[e] = p;
      cc[e] = pks[p];
    }
    PROC8P(cc, pp, k1, k)
  }
  FLUSH();
  __syncthreads();  // scan buffers dead; merge overlay usable

  MERGE_TREE()

  if (j == 0) {
    const unsigned mq = sidx[s];
    float* ob = obase + mq;
#pragma unroll
    for (int r = 0; r < 8; r++) {
      unsigned i0 = (unsigned)sidx[id[2 * r] & (N_ - 1)];
      unsigned i1 = (unsigned)sidx[id[2 * r + 1] & (N_ - 1)];
      ob[(size_t)r * N_] = __uint_as_float(i0 | (i1 << 16));
    }
  }
}

// ---------------- K_fe: gather + fe + shortcut GEMM (verified) ----------------
__global__ __launch_bounds__(NTHR, 2) void k_fe(
    const float4* __restrict__ pk, const float4* __restrict__ prm,
    const float* __restrict__ feature, const float* __restrict__ wsM,
    const float* __restrict__ bs, float* __restrict__ out) {
  const int blk = blockIdx.x;
  const int b  = blk / BLOCKS_PER_B;
  const int n0 = (blk % BLOCKS_PER_B) * QPB;
  const int t = threadIdx.x;
  const int q = t & 63;
  const int j = __builtin_amdgcn_readfirstlane(t >> 6);
  const size_t bb = (size_t)b << 13;
  const float INF = __uint_as_float(0x7f800000u);

  __shared__ float4 prmL[2 * HDIM];
  __shared__ float gp[4 * KNN * QPB];
  __shared__ float feL[DIN * QPB];
  __shared__ alignas(16) float wsL[DOUT * DIN];

  for (int i = t; i < 2 * HDIM; i += NTHR) prmL[i] = prm[i];
  for (int i = t; i < DOUT * DIN / 4; i += NTHR)
    ((float4*)wsL)[i] = ((const float4*)wsM)[i];
#pragma unroll
  for (int r = 0; r < 8; r++) {
    int c = j * 8 + r;
    feL[c * QPB + q] = feature[(size_t)(b * DIN + c) * N_ + n0 + q];
  }

  const float4 qv = pk[bb + n0 + q];
  const float qx = qv.x, qy = qv.y, qz = qv.z;

  float* ob = out + (size_t)b * DOUT * N_ + n0 + q;

  unsigned prb = __float_as_uint(ob[(size_t)j * N_]);
#pragma unroll
  for (int kk = 0; kk < 2; kk++) {
    int k = j * 2 + kk;
    int m = (int)((kk ? (prb >> 16) : prb) & 0xFFFFu) & (N_ - 1);
    float4 c = pk[bb + m];
    float dx = __fsub_rn(c.x, qx), dy = __fsub_rn(c.y, qy), dz = __fsub_rn(c.z, qz);
    float dsq = __fadd_rn(__fadd_rn(__fmul_rn(dx, dx), __fmul_rn(dy, dy)),
                          __fmul_rn(dz, dz));
    gp[k * QPB + q] = c.x;
    gp[(KNN + k) * QPB + q] = c.y;
    gp[(2 * KNN + k) * QPB + q] = c.z;
    gp[(3 * KNN + k) * QPB + q] = dsq;
  }
  __syncthreads();

  float fo[8];
  {
    float nx[KNN], ny[KNN], nz[KNN], nd[KNN];
#pragma unroll
    for (int k = 0; k < KNN; k++) {
      nx[k] = gp[k * QPB + q];
      ny[k] = gp[(KNN + k) * QPB + q];
      nz[k] = gp[(2 * KNN + k) * QPB + q];
      nd[k] = gp[(3 * KNN + k) * QPB + q];
    }
#pragma unroll
    for (int oi = 0; oi < 8; oi++) {
      int o = j * 8 + oi;
      float4 pA = prmL[o], pB = prmL[HDIM + o];
      float basev = fmaf(qz, pA.z, fmaf(qy, pA.y, fmaf(qx, pA.x, pA.w)));
      float mx = -INF;
#pragma unroll
      for (int k = 0; k < KNN; k++) {
        float tv = fmaf(nz[k], pB.z,
                   fmaf(ny[k], pB.y,
                   fmaf(nx[k], pB.x, __fmul_rn(nd[k], pB.w))));
        mx = fmaxf(mx, tv);
      }
      fo[oi] = basev + mx;
    }
  }

  float acc[16];
#pragma unroll
  for (int oi = 0; oi < 16; oi++) acc[oi] = 0.f;
  for (int c4 = 0; c4 < DIN / 4; c4++) {
    float f0 = feL[(4 * c4 + 0) * QPB + q];
    float f1 = feL[(4 * c4 + 1) * QPB + q];
    float f2 = feL[(4 * c4 + 2) * QPB + q];
    float f3 = feL[(4 * c4 + 3) * QPB + q];
#pragma unroll
    for (int oi = 0; oi < 16; oi++) {
      int o = (oi < 8) ? (j * 8 + oi) : (64 + j * 8 + oi - 8);
      float4 w = ((const float4*)(wsL + o * DIN))[c4];
      acc[oi] = fmaf(w.x, f0, acc[oi]);
      acc[oi] = fmaf(w.y, f1, acc[oi]);
      acc[oi] = fmaf(w.z, f2, acc[oi]);
      acc[oi] = fmaf(w.w, f3, acc[oi]);
    }
  }
#pragma unroll
  for (int oi = 0; oi < 16; oi++) {
    int o = (oi < 8) ? (j * 8 + oi) : (64 + j * 8 + oi - 8);
    ob[(size_t)o * N_] = acc[oi] + bs[o] + fo[oi & 7];
  }
}

extern "C" void kernel_launch(void* const* d_in, const int* in_sizes, int n_in,
                              void* d_out, int out_size, void* d_ws, size_t ws_size,
                              hipStream_t stream) {
  const float* xyz     = (const float*)d_in[0];
  const float* feature = (const float*)d_in[1];
  const float* w1 = (const float*)d_in[2];
  const float* b1 = (const float*)d_in[3];
  const float* w2 = (const float*)d_in[4];
  const float* b2 = (const float*)d_in[5];
  const float* w3 = (const float*)d_in[6];
  const float* b3 = (const float*)d_in[7];
  const float* wsM = (const float*)d_in[8];
  const float* bs  = (const float*)d_in[9];
  float* out = (float*)d_out;

  float4* prm = (float4*)d_ws;
  float4* pkB = (float4*)((char*)d_ws + 8192);

  hipLaunchKernelGGL(k_zero, dim3(B_), dim3(256), 0, stream, out);
  hipLaunchKernelGGL(k_prep, dim3(128), dim3(256), 0, stream,
                     xyz, w1, b1, w2, b2, w3, b3, pkB, prm, out);
  hipLaunchKernelGGL(k_scatter, dim3(128), dim3(256), 0, stream, pkB, out);
  hipLaunchKernelGGL(k_seed, dim3(B_ * BLOCKS_PER_B), dim3(NTHR), 0, stream, out);
  hipLaunchKernelGGL(k_expand, dim3(B_ * BLOCKS_PER_B), dim3(NTHR), 0, stream, out);
  hipLaunchKernelGGL(k_fe, dim3(B_ * BLOCKS_PER_B), dim3(NTHR), 0, stream,
                     pkB, prm, feature, wsM, bs, out);
}